// Round 1
// baseline (1470.445 us; speedup 1.0000x reference)
//
#include <hip/hip_runtime.h>
#include <math.h>

// Problem constants
#define NB 64    // N batch
#define LL 128   // L
#define DV 16
#define DD 256   // D
#define HH 8     // heads
#define DK 32    // D/H
#define FF 1024
#define LC 3
#define KNN 6
#define MS 16

// ---------------------------------------------------------------------------
// Input projection: h[m][j] = sum_t veh[m][t]*Wp[t][j] + bp[j]   (m<8192,j<256)
// ---------------------------------------------------------------------------
__global__ __launch_bounds__(256)
void proj_kernel(const float* __restrict__ veh, const float* __restrict__ Wp,
                 const float* __restrict__ bp, float* __restrict__ h) {
    int m = blockIdx.x;
    int j = threadIdx.x;
    __shared__ float vrow[DV];
    if (j < DV) vrow[j] = veh[m * DV + j];
    __syncthreads();
    float acc = bp[j];
#pragma unroll
    for (int t = 0; t < DV; ++t) acc += vrow[t] * Wp[t * DD + j];
    h[m * DD + j] = acc;
}

// ---------------------------------------------------------------------------
// kNN mask: per row (n,r) find K=6 smallest dist (ties -> lowest index, same
// as jax.lax.top_k on -dist). mask==1 means blocked.
// ---------------------------------------------------------------------------
__global__ __launch_bounds__(64)
void knn_kernel(const float* __restrict__ edges, unsigned char* __restrict__ mask) {
    int row = blockIdx.x * 64 + threadIdx.x;   // 0..8191 = n*L + r
    const float* dr = edges + (size_t)row * LL * 4;   // component 0, stride 4
    int sel[KNN];
#pragma unroll
    for (int k = 0; k < KNN; ++k) {
        float best = 3.4e38f;
        int bi = 0;
        for (int c = 0; c < LL; ++c) {
            bool skip = false;
#pragma unroll
            for (int t = 0; t < KNN; ++t)
                if (t < k) skip |= (sel[t] == c);
            float dc = dr[c * 4];
            if (!skip && dc < best) { best = dc; bi = c; }
        }
        sel[k] = bi;
    }
    unsigned char* mrow = mask + (size_t)row * LL;
    for (int c = 0; c < LL; ++c) mrow[c] = 1;
#pragma unroll
    for (int k = 0; k < KNN; ++k) mrow[sel[k]] = 0;
}

// ---------------------------------------------------------------------------
// Tiled f32 GEMM: C = A(MxK,row-major) @ B(KxN,row-major) [+ bias]
// MODE 0: plain (+bias). MODE 1: +bias +relu. MODE 2: head-major remap (QKV,
//         N must be 256): out[((n*8+hh)*128 + r)*32 + dk]
// Tile 64x64, BK=16, 256 threads, 4x4 microtile.
// ---------------------------------------------------------------------------
template <int MODE>
__global__ __launch_bounds__(256)
void gemm64(const float* __restrict__ A, const float* __restrict__ B,
            const float* __restrict__ bias, float* __restrict__ C,
            int M, int N, int K) {
    __shared__ float As[16][68];   // [k][m], padded
    __shared__ float Bs[16][64];   // [k][n]
    int tid = threadIdx.x;
    int tr = tid >> 4;             // 0..15
    int tc = tid & 15;             // 0..15
    int m0 = blockIdx.y * 64;
    int n0 = blockIdx.x * 64;

    int arow = tid >> 2;           // 0..63
    int akq  = (tid & 3) * 4;      // 0,4,8,12
    int brow = tid >> 4;           // 0..15
    int bcol = (tid & 15) * 4;     // 0..60

    float acc[4][4];
#pragma unroll
    for (int i = 0; i < 4; ++i)
#pragma unroll
        for (int j = 0; j < 4; ++j) acc[i][j] = 0.f;

    for (int k0 = 0; k0 < K; k0 += 16) {
        float4 av = *reinterpret_cast<const float4*>(&A[(size_t)(m0 + arow) * K + k0 + akq]);
        float4 bv = *reinterpret_cast<const float4*>(&B[(size_t)(k0 + brow) * N + n0 + bcol]);
        __syncthreads();
        As[akq + 0][arow] = av.x;
        As[akq + 1][arow] = av.y;
        As[akq + 2][arow] = av.z;
        As[akq + 3][arow] = av.w;
        *reinterpret_cast<float4*>(&Bs[brow][bcol]) = bv;
        __syncthreads();
#pragma unroll
        for (int kk = 0; kk < 16; ++kk) {
            float4 a4 = *reinterpret_cast<const float4*>(&As[kk][tr * 4]);
            float4 b4 = *reinterpret_cast<const float4*>(&Bs[kk][tc * 4]);
            float a_[4] = {a4.x, a4.y, a4.z, a4.w};
            float b_[4] = {b4.x, b4.y, b4.z, b4.w};
#pragma unroll
            for (int i = 0; i < 4; ++i)
#pragma unroll
                for (int j = 0; j < 4; ++j) acc[i][j] += a_[i] * b_[j];
        }
    }

#pragma unroll
    for (int i = 0; i < 4; ++i) {
        int m = m0 + tr * 4 + i;
#pragma unroll
        for (int j = 0; j < 4; ++j) {
            int col = n0 + tc * 4 + j;
            float v = acc[i][j];
            if (bias) v += bias[col];
            if (MODE == 1) v = fmaxf(v, 0.f);
            if (MODE == 2) {
                int n = m >> 7, r = m & 127;
                int hh = col >> 5, dk = col & 31;
                C[(((size_t)(n * HH + hh) * LL + r) * DK) + dk] = v;
            } else {
                C[(size_t)m * N + col] = v;
            }
        }
    }
}

// ---------------------------------------------------------------------------
// Fused: dot(q,k)*scale -> mixer MLP -> mask -> softmax -> attn weights
// One block per (n,h). 128 threads (thread = column c).
// ---------------------------------------------------------------------------
__global__ __launch_bounds__(128)
void score_softmax(const float* __restrict__ qh, const float* __restrict__ kh,
                   const float* __restrict__ edges, const unsigned char* __restrict__ mask,
                   const float* __restrict__ m1w, const float* __restrict__ m1b,
                   const float* __restrict__ m2w, const float* __restrict__ m2b,
                   float* __restrict__ attw) {
    int bh = blockIdx.x;          // n*H + hh
    int n = bh >> 3, hh = bh & 7;
    int c = threadIdx.x;          // 0..127
    __shared__ float Qt[128 * 33];
    __shared__ float Kt[128 * 33];
    __shared__ float w10[MS], w11[MS], b1s[MS], w2s[MS];
    __shared__ float red[4];

    const float* qb = qh + (size_t)bh * LL * DK;
    const float* kb = kh + (size_t)bh * LL * DK;
    for (int idx = c; idx < 1024; idx += 128) {
        float4 qv = reinterpret_cast<const float4*>(qb)[idx];
        float4 kv = reinterpret_cast<const float4*>(kb)[idx];
        int row = idx >> 3, col = (idx & 7) * 4;
        float* qd = &Qt[row * 33 + col];
        qd[0] = qv.x; qd[1] = qv.y; qd[2] = qv.z; qd[3] = qv.w;
        float* kd = &Kt[row * 33 + col];
        kd[0] = kv.x; kd[1] = kv.y; kd[2] = kv.z; kd[3] = kv.w;
    }
    if (c < MS) {
        w10[c] = m1w[(hh * 2 + 0) * MS + c];
        w11[c] = m1w[(hh * 2 + 1) * MS + c];
        b1s[c] = m1b[hh * MS + c];
        w2s[c] = m2w[hh * MS + c];
    }
    __syncthreads();
    float b2v = m2b[hh];
    const float scale = 0.17677669529663687f;   // 1/sqrt(32)
    int lane = c & 63, wid = c >> 6;
    unsigned char mloc; // per-c mask reused per r row below (mask row depends on r, reload)

    for (int r = 0; r < LL; ++r) {
        float dot = 0.f;
#pragma unroll
        for (int d = 0; d < DK; ++d) dot += Qt[r * 33 + d] * Kt[c * 33 + d];
        dot *= scale;
        float cost = edges[(((size_t)(n * LL + r) * LL) + c) * 4];
        float s = b2v;
#pragma unroll
        for (int m = 0; m < MS; ++m)
            s += fmaxf(dot * w10[m] + cost * w11[m] + b1s[m], 0.f) * w2s[m];
        mloc = mask[(size_t)(n * LL + r) * LL + c];
        if (mloc) s = -1e9f;

        // softmax over the 128 columns
        float mx = s;
#pragma unroll
        for (int o = 32; o; o >>= 1) mx = fmaxf(mx, __shfl_xor(mx, o));
        if (lane == 0) red[wid] = mx;
        __syncthreads();
        mx = fmaxf(red[0], red[1]);
        float e = expf(s - mx);
        float sum = e;
#pragma unroll
        for (int o = 32; o; o >>= 1) sum += __shfl_xor(sum, o);
        if (lane == 0) red[2 + wid] = sum;
        __syncthreads();
        sum = red[2] + red[3];
        attw[((size_t)bh * LL + r) * LL + c] = e / sum;
        __syncthreads();   // protect red[] reuse next iteration
    }
}

// ---------------------------------------------------------------------------
// att = w @ v  per (n,h);  output written directly in (N, L, D) layout
// ---------------------------------------------------------------------------
__global__ __launch_bounds__(256)
void attn_v(const float* __restrict__ attw, const float* __restrict__ vh,
            float* __restrict__ attc) {
    int bh = blockIdx.x;
    int n = bh >> 3, hh = bh & 7;
    __shared__ float V[128 * 33];
    const float* vb = vh + (size_t)bh * LL * DK;
    int tid = threadIdx.x;
    for (int idx = tid; idx < 1024; idx += 256) {
        float4 vv = reinterpret_cast<const float4*>(vb)[idx];
        int row = idx >> 3, col = (idx & 7) * 4;
        float* vd = &V[row * 33 + col];
        vd[0] = vv.x; vd[1] = vv.y; vd[2] = vv.z; vd[3] = vv.w;
    }
    __syncthreads();
    int d = tid & 31, rg = tid >> 5;   // rg 0..7
    for (int rr = 0; rr < 16; ++rr) {
        int r = rg * 16 + rr;
        const float4* wrow = reinterpret_cast<const float4*>(attw + ((size_t)bh * LL + r) * LL);
        float acc = 0.f;
#pragma unroll
        for (int cb = 0; cb < 32; ++cb) {
            float4 w4 = wrow[cb];
            acc += w4.x * V[(cb * 4 + 0) * 33 + d];
            acc += w4.y * V[(cb * 4 + 1) * 33 + d];
            acc += w4.z * V[(cb * 4 + 2) * 33 + d];
            acc += w4.w * V[(cb * 4 + 3) * 33 + d];
        }
        attc[((size_t)(n * LL + r)) * DD + hh * DK + d] = acc;
    }
}

// ---------------------------------------------------------------------------
// out = LayerNorm(a + b) * g + be   ; one block per row, 256 threads
// ---------------------------------------------------------------------------
__global__ __launch_bounds__(256)
void add_ln(const float* __restrict__ a, const float* __restrict__ b,
            const float* __restrict__ g, const float* __restrict__ be,
            float* __restrict__ out) {
    int m = blockIdx.x;
    int j = threadIdx.x;
    float x = a[(size_t)m * DD + j] + b[(size_t)m * DD + j];
    __shared__ float red[4];
    int wid = j >> 6;
    float s = x;
#pragma unroll
    for (int o = 32; o; o >>= 1) s += __shfl_xor(s, o);
    if ((j & 63) == 0) red[wid] = s;
    __syncthreads();
    float mean = (red[0] + red[1] + red[2] + red[3]) * (1.0f / 256.0f);
    float d = x - mean;
    float s2 = d * d;
#pragma unroll
    for (int o = 32; o; o >>= 1) s2 += __shfl_xor(s2, o);
    __syncthreads();
    if ((j & 63) == 0) red[wid] = s2;
    __syncthreads();
    float var = (red[0] + red[1] + red[2] + red[3]) * (1.0f / 256.0f);
    out[(size_t)m * DD + j] = d / sqrtf(var + 1e-5f) * g[j] + be[j];
}

// ---------------------------------------------------------------------------
extern "C" void kernel_launch(void* const* d_in, const int* in_sizes, int n_in,
                              void* d_out, int out_size, void* d_ws, size_t ws_size,
                              hipStream_t stream) {
    const float* vehicles = (const float*)d_in[0];
    const float* fleet    = (const float*)d_in[1];
    const float* Wproj    = (const float*)d_in[2];
    const float* bproj    = (const float*)d_in[3];
    const float* Wq       = (const float*)d_in[4];
    const float* Wk       = (const float*)d_in[5];
    const float* Wv       = (const float*)d_in[6];
    const float* m1w      = (const float*)d_in[7];
    const float* m1b      = (const float*)d_in[8];
    const float* m2w      = (const float*)d_in[9];
    const float* m2b      = (const float*)d_in[10];
    const float* Wo       = (const float*)d_in[11];
    const float* bo       = (const float*)d_in[12];
    const float* n1_g     = (const float*)d_in[13];
    const float* n1_b     = (const float*)d_in[14];
    const float* ff1_w    = (const float*)d_in[15];
    const float* ff1_b    = (const float*)d_in[16];
    const float* ff2_w    = (const float*)d_in[17];
    const float* ff2_b    = (const float*)d_in[18];
    const float* n2_g     = (const float*)d_in[19];
    const float* n2_b     = (const float*)d_in[20];

    const size_t MROWS = (size_t)NB * LL;          // 8192
    const size_t HSZ   = MROWS * DD;               // 2,097,152 floats
    const size_t BIGSZ = (size_t)NB * HH * LL * LL; // 8,388,608 floats

    float* ws   = (float*)d_ws;
    float* h    = ws;
    float* qh   = h    + HSZ;
    float* kh   = qh   + HSZ;
    float* vh   = kh   + HSZ;
    float* attc = vh   + HSZ;
    float* tmp  = attc + HSZ;
    float* big  = tmp  + HSZ;                      // attw / ffmid (shared region)
    unsigned char* mask = (unsigned char*)(big + BIGSZ);

    // 1) input projection
    proj_kernel<<<MROWS, 256, 0, stream>>>(vehicles, Wproj, bproj, h);
    // 2) kNN mask
    knn_kernel<<<128, 64, 0, stream>>>(fleet, mask);

    dim3 g4(4, 128);    // N=256 tiles
    dim3 g16(16, 128);  // N=1024 tiles

    for (int i = 0; i < LC; ++i) {
        const float* Wq_i = Wq + (size_t)i * DD * DD;
        const float* Wk_i = Wk + (size_t)i * DD * DD;
        const float* Wv_i = Wv + (size_t)i * DD * DD;

        gemm64<2><<<g4, 256, 0, stream>>>(h, Wq_i, nullptr, qh, MROWS, DD, DD);
        gemm64<2><<<g4, 256, 0, stream>>>(h, Wk_i, nullptr, kh, MROWS, DD, DD);
        gemm64<2><<<g4, 256, 0, stream>>>(h, Wv_i, nullptr, vh, MROWS, DD, DD);

        score_softmax<<<NB * HH, 128, 0, stream>>>(
            qh, kh, fleet, mask,
            m1w + (size_t)i * HH * 2 * MS, m1b + (size_t)i * HH * MS,
            m2w + (size_t)i * HH * MS,     m2b + (size_t)i * HH,
            big);

        attn_v<<<NB * HH, 256, 0, stream>>>(big, vh, attc);

        gemm64<0><<<g4, 256, 0, stream>>>(attc, Wo + (size_t)i * DD * DD,
                                          bo + (size_t)i * DD, tmp, MROWS, DD, DD);
        add_ln<<<MROWS, 256, 0, stream>>>(h, tmp, n1_g + (size_t)i * DD,
                                          n1_b + (size_t)i * DD, h);

        gemm64<1><<<g16, 256, 0, stream>>>(h, ff1_w + (size_t)i * DD * FF,
                                           ff1_b + (size_t)i * FF, big, MROWS, FF, DD);
        gemm64<0><<<g4, 256, 0, stream>>>(big, ff2_w + (size_t)i * FF * DD,
                                          ff2_b + (size_t)i * DD, tmp, MROWS, DD, FF);

        float* dst = (i == LC - 1) ? (float*)d_out : h;
        add_ln<<<MROWS, 256, 0, stream>>>(h, tmp, n2_g + (size_t)i * DD,
                                          n2_b + (size_t)i * DD, dst);
    }
}

// Round 2
// 1188.431 us; speedup vs baseline: 1.2373x; 1.2373x over previous
//
#include <hip/hip_runtime.h>
#include <math.h>

// Problem constants
#define NB 64    // N batch
#define LL 128   // L
#define DV 16
#define DD 256   // D
#define HH 8     // heads
#define DK 32    // D/H
#define FF 1024
#define LC 3
#define KNN 6
#define MS 16

// ---------------------------------------------------------------------------
// Input projection: h[m][j] = sum_t veh[m][t]*Wp[t][j] + bp[j]   (m<8192,j<256)
// ---------------------------------------------------------------------------
__global__ __launch_bounds__(256)
void proj_kernel(const float* __restrict__ veh, const float* __restrict__ Wp,
                 const float* __restrict__ bp, float* __restrict__ h) {
    int m = blockIdx.x;
    int j = threadIdx.x;
    __shared__ float vrow[DV];
    if (j < DV) vrow[j] = veh[m * DV + j];
    __syncthreads();
    float acc = bp[j];
#pragma unroll
    for (int t = 0; t < DV; ++t) acc += vrow[t] * Wp[t * DD + j];
    h[m * DD + j] = acc;
}

// ---------------------------------------------------------------------------
// Pack cost = edges[...,0] into contiguous (N,L,L) buffer.
// cost[4t+j] = edges[(4t+j)*4] -> read 4 float4, keep .x of each.
// ---------------------------------------------------------------------------
__global__ __launch_bounds__(256)
void pack_cost(const float* __restrict__ edges, float* __restrict__ cost) {
    int t = blockIdx.x * 256 + threadIdx.x;    // < 262144
    const float4* e4 = reinterpret_cast<const float4*>(edges) + (size_t)t * 4;
    float4 a = e4[0], b = e4[1], c = e4[2], d = e4[3];
    reinterpret_cast<float4*>(cost)[t] = make_float4(a.x, b.x, c.x, d.x);
}

// ---------------------------------------------------------------------------
// kNN mask, wave-parallel: one wave per row; 6 rounds of shfl min-with-index.
// Tie-break: lowest index (matches stable jax.lax.top_k on -dist).
// mask==1 -> blocked.
// ---------------------------------------------------------------------------
__global__ __launch_bounds__(256)
void knn2(const float* __restrict__ cost, unsigned char* __restrict__ mask) {
    int row = blockIdx.x * 4 + (threadIdx.x >> 6);   // 0..8191
    int lane = threadIdx.x & 63;
    const float* cr = cost + (size_t)row * LL;
    float v0 = cr[lane], v1 = cr[lane + 64];
    int i0 = lane, i1 = lane + 64;
    bool s0 = false, s1 = false;
#pragma unroll
    for (int k = 0; k < KNN; ++k) {
        float v; int i;
        if (v1 < v0) { v = v1; i = i1; } else { v = v0; i = i0; }
#pragma unroll
        for (int o = 1; o < 64; o <<= 1) {
            float ov = __shfl_xor(v, o);
            int oi = __shfl_xor(i, o);
            if (ov < v || (ov == v && oi < i)) { v = ov; i = oi; }
        }
        if (i == i0) { s0 = true; v0 = 3.4e38f; }
        if (i == i1) { s1 = true; v1 = 3.4e38f; }
    }
    mask[(size_t)row * LL + lane]      = s0 ? 0 : 1;
    mask[(size_t)row * LL + lane + 64] = s1 ? 0 : 1;
}

// ---------------------------------------------------------------------------
// Tiled f32 GEMM: C = A(MxK,row-major) @ B(KxN,row-major) [+ bias]
// MODE 0: plain (+bias). MODE 1: +bias +relu. MODE 2: head-major remap (QKV,
//         N must be 256): out[((n*8+hh)*128 + r)*32 + dk]
// Tile 64x64, BK=16, 256 threads, 4x4 microtile.
// ---------------------------------------------------------------------------
template <int MODE>
__global__ __launch_bounds__(256)
void gemm64(const float* __restrict__ A, const float* __restrict__ B,
            const float* __restrict__ bias, float* __restrict__ C,
            int M, int N, int K) {
    __shared__ float As[16][68];   // [k][m], padded
    __shared__ float Bs[16][64];   // [k][n]
    int tid = threadIdx.x;
    int tr = tid >> 4;             // 0..15
    int tc = tid & 15;             // 0..15
    int m0 = blockIdx.y * 64;
    int n0 = blockIdx.x * 64;

    int arow = tid >> 2;           // 0..63
    int akq  = (tid & 3) * 4;      // 0,4,8,12
    int brow = tid >> 4;           // 0..15
    int bcol = (tid & 15) * 4;     // 0..60

    float acc[4][4];
#pragma unroll
    for (int i = 0; i < 4; ++i)
#pragma unroll
        for (int j = 0; j < 4; ++j) acc[i][j] = 0.f;

    for (int k0 = 0; k0 < K; k0 += 16) {
        float4 av = *reinterpret_cast<const float4*>(&A[(size_t)(m0 + arow) * K + k0 + akq]);
        float4 bv = *reinterpret_cast<const float4*>(&B[(size_t)(k0 + brow) * N + n0 + bcol]);
        __syncthreads();
        As[akq + 0][arow] = av.x;
        As[akq + 1][arow] = av.y;
        As[akq + 2][arow] = av.z;
        As[akq + 3][arow] = av.w;
        *reinterpret_cast<float4*>(&Bs[brow][bcol]) = bv;
        __syncthreads();
#pragma unroll
        for (int kk = 0; kk < 16; ++kk) {
            float4 a4 = *reinterpret_cast<const float4*>(&As[kk][tr * 4]);
            float4 b4 = *reinterpret_cast<const float4*>(&Bs[kk][tc * 4]);
            float a_[4] = {a4.x, a4.y, a4.z, a4.w};
            float b_[4] = {b4.x, b4.y, b4.z, b4.w};
#pragma unroll
            for (int i = 0; i < 4; ++i)
#pragma unroll
                for (int j = 0; j < 4; ++j) acc[i][j] += a_[i] * b_[j];
        }
    }

#pragma unroll
    for (int i = 0; i < 4; ++i) {
        int m = m0 + tr * 4 + i;
#pragma unroll
        for (int j = 0; j < 4; ++j) {
            int col = n0 + tc * 4 + j;
            float v = acc[i][j];
            if (bias) v += bias[col];
            if (MODE == 1) v = fmaxf(v, 0.f);
            if (MODE == 2) {
                int n = m >> 7, r = m & 127;
                int hh = col >> 5, dk = col & 31;
                C[(((size_t)(n * HH + hh) * LL + r) * DK) + dk] = v;
            } else {
                C[(size_t)m * N + col] = v;
            }
        }
    }
}

// ---------------------------------------------------------------------------
// Fused: dot(q,k)*scale -> mixer MLP -> mask -> softmax -> attn weights.
// Wave-parallel v2: grid N*H*4, block 256 (4 waves). Each block owns 32 rows
// of one (n,h); each wave owns 8 rows. Lane l handles cols {l, l+64}.
// K rows for the lane's two columns live in registers; Q broadcast from LDS.
// No barriers in the row loop (wave-synchronous shfl softmax).
// ---------------------------------------------------------------------------
__global__ __launch_bounds__(256, 4)
void score_softmax2(const float* __restrict__ qh, const float* __restrict__ kh,
                    const float* __restrict__ cost, const unsigned char* __restrict__ mask,
                    const float* __restrict__ m1w, const float* __restrict__ m1b,
                    const float* __restrict__ m2w, const float* __restrict__ m2b,
                    float* __restrict__ attw) {
    int blk = blockIdx.x;            // 0 .. N*H*4-1
    int bh  = blk >> 2;              // n*H + hh
    int rq  = blk & 3;               // row quarter (32 rows)
    int n = bh >> 3, hh = bh & 7;
    int tid = threadIdx.x;
    int lane = tid & 63, wid = tid >> 6;

    __shared__ float Qt[32][33];
    __shared__ float w10[MS], w11[MS], b1s[MS], w2s[MS];

    // load 32 Q rows (1024 floats): 256 threads x 1 float4
    {
        const float4* qb4 = reinterpret_cast<const float4*>(
            qh + ((size_t)bh * LL + rq * 32) * DK);
        float4 qv = qb4[tid];
        int row = tid >> 3, col = (tid & 7) * 4;
        Qt[row][col] = qv.x; Qt[row][col + 1] = qv.y;
        Qt[row][col + 2] = qv.z; Qt[row][col + 3] = qv.w;
    }
    if (tid < MS) {
        w10[tid] = m1w[(hh * 2 + 0) * MS + tid];
        w11[tid] = m1w[(hh * 2 + 1) * MS + tid];
        b1s[tid] = m1b[hh * MS + tid];
        w2s[tid] = m2w[hh * MS + tid];
    }
    // K rows for this lane's two columns -> registers
    const float* kb = kh + (size_t)bh * LL * DK;
    float k0[DK], k1[DK];
    {
        const float4* k4a = reinterpret_cast<const float4*>(kb + (size_t)lane * DK);
        const float4* k4b = reinterpret_cast<const float4*>(kb + (size_t)(lane + 64) * DK);
#pragma unroll
        for (int j = 0; j < 8; ++j) {
            float4 a = k4a[j], b = k4b[j];
            k0[j * 4] = a.x; k0[j * 4 + 1] = a.y; k0[j * 4 + 2] = a.z; k0[j * 4 + 3] = a.w;
            k1[j * 4] = b.x; k1[j * 4 + 1] = b.y; k1[j * 4 + 2] = b.z; k1[j * 4 + 3] = b.w;
        }
    }
    __syncthreads();

    float b2v = m2b[hh];
    const float scale = 0.17677669529663687f;   // 1/sqrt(32)

    for (int i = 0; i < 8; ++i) {
        int rloc = wid * 8 + i;
        int r = rq * 32 + rloc;
        float d0 = 0.f, d1 = 0.f;
#pragma unroll
        for (int d = 0; d < DK; ++d) {
            float qd = Qt[rloc][d];
            d0 += qd * k0[d];
            d1 += qd * k1[d];
        }
        d0 *= scale; d1 *= scale;
        size_t rowoff = ((size_t)n * LL + r) * LL;
        float c0 = cost[rowoff + lane], c1 = cost[rowoff + 64 + lane];
        float s0 = b2v, s1 = b2v;
#pragma unroll
        for (int m = 0; m < MS; ++m) {
            s0 += fmaxf(d0 * w10[m] + c0 * w11[m] + b1s[m], 0.f) * w2s[m];
            s1 += fmaxf(d1 * w10[m] + c1 * w11[m] + b1s[m], 0.f) * w2s[m];
        }
        if (mask[rowoff + lane])      s0 = -1e9f;
        if (mask[rowoff + 64 + lane]) s1 = -1e9f;

        float mx = fmaxf(s0, s1);
#pragma unroll
        for (int o = 32; o; o >>= 1) mx = fmaxf(mx, __shfl_xor(mx, o));
        float e0 = __expf(s0 - mx), e1 = __expf(s1 - mx);
        float sum = e0 + e1;
#pragma unroll
        for (int o = 32; o; o >>= 1) sum += __shfl_xor(sum, o);
        float inv = 1.f / sum;
        float* arow = attw + ((size_t)bh * LL + r) * LL;
        arow[lane]      = e0 * inv;
        arow[lane + 64] = e1 * inv;
    }
}

// ---------------------------------------------------------------------------
// att = w @ v  per (n,h);  output written directly in (N, L, D) layout
// ---------------------------------------------------------------------------
__global__ __launch_bounds__(256)
void attn_v(const float* __restrict__ attw, const float* __restrict__ vh,
            float* __restrict__ attc) {
    int bh = blockIdx.x;
    int n = bh >> 3, hh = bh & 7;
    __shared__ float V[128 * 33];
    const float* vb = vh + (size_t)bh * LL * DK;
    int tid = threadIdx.x;
    for (int idx = tid; idx < 1024; idx += 256) {
        float4 vv = reinterpret_cast<const float4*>(vb)[idx];
        int row = idx >> 3, col = (idx & 7) * 4;
        float* vd = &V[row * 33 + col];
        vd[0] = vv.x; vd[1] = vv.y; vd[2] = vv.z; vd[3] = vv.w;
    }
    __syncthreads();
    int d = tid & 31, rg = tid >> 5;   // rg 0..7
    for (int rr = 0; rr < 16; ++rr) {
        int r = rg * 16 + rr;
        const float4* wrow = reinterpret_cast<const float4*>(attw + ((size_t)bh * LL + r) * LL);
        float acc = 0.f;
#pragma unroll
        for (int cb = 0; cb < 32; ++cb) {
            float4 w4 = wrow[cb];
            acc += w4.x * V[(cb * 4 + 0) * 33 + d];
            acc += w4.y * V[(cb * 4 + 1) * 33 + d];
            acc += w4.z * V[(cb * 4 + 2) * 33 + d];
            acc += w4.w * V[(cb * 4 + 3) * 33 + d];
        }
        attc[((size_t)(n * LL + r)) * DD + hh * DK + d] = acc;
    }
}

// ---------------------------------------------------------------------------
// out = LayerNorm(a + b) * g + be   ; one block per row, 256 threads
// ---------------------------------------------------------------------------
__global__ __launch_bounds__(256)
void add_ln(const float* __restrict__ a, const float* __restrict__ b,
            const float* __restrict__ g, const float* __restrict__ be,
            float* __restrict__ out) {
    int m = blockIdx.x;
    int j = threadIdx.x;
    float x = a[(size_t)m * DD + j] + b[(size_t)m * DD + j];
    __shared__ float red[4];
    int wid = j >> 6;
    float s = x;
#pragma unroll
    for (int o = 32; o; o >>= 1) s += __shfl_xor(s, o);
    if ((j & 63) == 0) red[wid] = s;
    __syncthreads();
    float mean = (red[0] + red[1] + red[2] + red[3]) * (1.0f / 256.0f);
    float d = x - mean;
    float s2 = d * d;
#pragma unroll
    for (int o = 32; o; o >>= 1) s2 += __shfl_xor(s2, o);
    __syncthreads();
    if ((j & 63) == 0) red[wid] = s2;
    __syncthreads();
    float var = (red[0] + red[1] + red[2] + red[3]) * (1.0f / 256.0f);
    out[(size_t)m * DD + j] = d / sqrtf(var + 1e-5f) * g[j] + be[j];
}

// ---------------------------------------------------------------------------
extern "C" void kernel_launch(void* const* d_in, const int* in_sizes, int n_in,
                              void* d_out, int out_size, void* d_ws, size_t ws_size,
                              hipStream_t stream) {
    const float* vehicles = (const float*)d_in[0];
    const float* fleet    = (const float*)d_in[1];
    const float* Wproj    = (const float*)d_in[2];
    const float* bproj    = (const float*)d_in[3];
    const float* Wq       = (const float*)d_in[4];
    const float* Wk       = (const float*)d_in[5];
    const float* Wv       = (const float*)d_in[6];
    const float* m1w      = (const float*)d_in[7];
    const float* m1b      = (const float*)d_in[8];
    const float* m2w      = (const float*)d_in[9];
    const float* m2b      = (const float*)d_in[10];
    const float* Wo       = (const float*)d_in[11];
    const float* bo       = (const float*)d_in[12];
    const float* n1_g     = (const float*)d_in[13];
    const float* n1_b     = (const float*)d_in[14];
    const float* ff1_w    = (const float*)d_in[15];
    const float* ff1_b    = (const float*)d_in[16];
    const float* ff2_w    = (const float*)d_in[17];
    const float* ff2_b    = (const float*)d_in[18];
    const float* n2_g     = (const float*)d_in[19];
    const float* n2_b     = (const float*)d_in[20];

    const size_t MROWS = (size_t)NB * LL;           // 8192
    const size_t HSZ   = MROWS * DD;                // 2,097,152 floats
    const size_t BIGSZ = (size_t)NB * HH * LL * LL; // 8,388,608 floats
    const size_t CSZ   = (size_t)NB * LL * LL;      // 1,048,576 floats

    float* ws   = (float*)d_ws;
    float* h    = ws;
    float* qh   = h    + HSZ;
    float* kh   = qh   + HSZ;
    float* vh   = kh   + HSZ;
    float* attc = vh   + HSZ;
    float* tmp  = attc + HSZ;
    float* big  = tmp  + HSZ;                       // attw / ffmid (shared region)
    float* cost = big  + BIGSZ;
    unsigned char* mask = (unsigned char*)(cost + CSZ);

    // 1) pack cost, input projection, kNN mask
    pack_cost<<<1024, 256, 0, stream>>>(fleet, cost);
    proj_kernel<<<MROWS, 256, 0, stream>>>(vehicles, Wproj, bproj, h);
    knn2<<<2048, 256, 0, stream>>>(cost, mask);

    dim3 g4(4, 128);    // N=256 tiles
    dim3 g16(16, 128);  // N=1024 tiles

    for (int i = 0; i < LC; ++i) {
        const float* Wq_i = Wq + (size_t)i * DD * DD;
        const float* Wk_i = Wk + (size_t)i * DD * DD;
        const float* Wv_i = Wv + (size_t)i * DD * DD;

        gemm64<2><<<g4, 256, 0, stream>>>(h, Wq_i, nullptr, qh, MROWS, DD, DD);
        gemm64<2><<<g4, 256, 0, stream>>>(h, Wk_i, nullptr, kh, MROWS, DD, DD);
        gemm64<2><<<g4, 256, 0, stream>>>(h, Wv_i, nullptr, vh, MROWS, DD, DD);

        score_softmax2<<<NB * HH * 4, 256, 0, stream>>>(
            qh, kh, cost, mask,
            m1w + (size_t)i * HH * 2 * MS, m1b + (size_t)i * HH * MS,
            m2w + (size_t)i * HH * MS,     m2b + (size_t)i * HH,
            big);

        attn_v<<<NB * HH, 256, 0, stream>>>(big, vh, attc);

        gemm64<0><<<g4, 256, 0, stream>>>(attc, Wo + (size_t)i * DD * DD,
                                          bo + (size_t)i * DD, tmp, MROWS, DD, DD);
        add_ln<<<MROWS, 256, 0, stream>>>(h, tmp, n1_g + (size_t)i * DD,
                                          n1_b + (size_t)i * DD, h);

        gemm64<1><<<g16, 256, 0, stream>>>(h, ff1_w + (size_t)i * DD * FF,
                                           ff1_b + (size_t)i * FF, big, MROWS, FF, DD);
        gemm64<0><<<g4, 256, 0, stream>>>(big, ff2_w + (size_t)i * FF * DD,
                                          ff2_b + (size_t)i * DD, tmp, MROWS, DD, FF);

        float* dst = (i == LC - 1) ? (float*)d_out : h;
        add_ln<<<MROWS, 256, 0, stream>>>(h, tmp, n2_g + (size_t)i * DD,
                                          n2_b + (size_t)i * DD, dst);
    }
}

// Round 3
// 543.976 us; speedup vs baseline: 2.7031x; 2.1847x over previous
//
#include <hip/hip_runtime.h>
#include <math.h>

// Problem constants
#define NB 64    // N batch
#define LL 128   // L
#define DV 16
#define DD 256   // D
#define HH 8     // heads
#define DK 32    // D/H
#define FF 1024
#define LC 3
#define KNN 6
#define MS 16

typedef __attribute__((ext_vector_type(8))) short s16x8;   // 8 bf16 (4 VGPR)
typedef __attribute__((ext_vector_type(4))) float f32x4;   // MFMA acc

static __device__ inline unsigned short f2b(float x) {
    union { float f; unsigned int u; } v; v.f = x;
    unsigned int r = (v.u + 0x7FFFu + ((v.u >> 16) & 1u)) >> 16;
    return (unsigned short)r;
}

// ---------------------------------------------------------------------------
// Input projection: h = veh @ Wp + bp ; writes f32 h and bf16 mirror hb
// ---------------------------------------------------------------------------
__global__ __launch_bounds__(256)
void proj_kernel(const float* __restrict__ veh, const float* __restrict__ Wp,
                 const float* __restrict__ bp, float* __restrict__ h,
                 unsigned short* __restrict__ hb) {
    int m = blockIdx.x;
    int j = threadIdx.x;
    __shared__ float vrow[DV];
    if (j < DV) vrow[j] = veh[m * DV + j];
    __syncthreads();
    float acc = bp[j];
#pragma unroll
    for (int t = 0; t < DV; ++t) acc += vrow[t] * Wp[t * DD + j];
    h[(size_t)m * DD + j] = acc;
    hb[(size_t)m * DD + j] = f2b(acc);
}

// ---------------------------------------------------------------------------
// Pack cost = edges[...,0] into contiguous (N,L,L)
// ---------------------------------------------------------------------------
__global__ __launch_bounds__(256)
void pack_cost(const float* __restrict__ edges, float* __restrict__ cost) {
    int t = blockIdx.x * 256 + threadIdx.x;
    const float4* e4 = reinterpret_cast<const float4*>(edges) + (size_t)t * 4;
    float4 a = e4[0], b = e4[1], c = e4[2], d = e4[3];
    reinterpret_cast<float4*>(cost)[t] = make_float4(a.x, b.x, c.x, d.x);
}

// ---------------------------------------------------------------------------
// kNN mask (wave-parallel, 6 rounds of shfl min-with-index)
// ---------------------------------------------------------------------------
__global__ __launch_bounds__(256)
void knn2(const float* __restrict__ cost, unsigned char* __restrict__ mask) {
    int row = blockIdx.x * 4 + (threadIdx.x >> 6);
    int lane = threadIdx.x & 63;
    const float* cr = cost + (size_t)row * LL;
    float v0 = cr[lane], v1 = cr[lane + 64];
    int i0 = lane, i1 = lane + 64;
    bool s0 = false, s1 = false;
#pragma unroll
    for (int k = 0; k < KNN; ++k) {
        float v; int i;
        if (v1 < v0) { v = v1; i = i1; } else { v = v0; i = i0; }
#pragma unroll
        for (int o = 1; o < 64; o <<= 1) {
            float ov = __shfl_xor(v, o);
            int oi = __shfl_xor(i, o);
            if (ov < v || (ov == v && oi < i)) { v = ov; i = oi; }
        }
        if (i == i0) { s0 = true; v0 = 3.4e38f; }
        if (i == i1) { s1 = true; v1 = 3.4e38f; }
    }
    mask[(size_t)row * LL + lane]      = s0 ? 0 : 1;
    mask[(size_t)row * LL + lane + 64] = s1 ? 0 : 1;
}

// ---------------------------------------------------------------------------
// Transpose + bf16-cast weights: in (LC, K, N) f32 -> out (LC, N, K) bf16
// ---------------------------------------------------------------------------
__global__ __launch_bounds__(256)
void transposeW(const float* __restrict__ in, unsigned short* __restrict__ out,
                int K, int N, long in_lstride, long out_lstride) {
    int l = blockIdx.z;
    const float* inp = in + (size_t)l * in_lstride;
    unsigned short* outp = out + (size_t)l * out_lstride;
    int tx = threadIdx.x & 31, ty = threadIdx.x >> 5;   // ty 0..7
    int k0 = blockIdx.y * 32, n0 = blockIdx.x * 32;
    __shared__ float T[32][33];
#pragma unroll
    for (int r = 0; r < 4; ++r)
        T[ty + r * 8][tx] = inp[(size_t)(k0 + ty + r * 8) * N + n0 + tx];
    __syncthreads();
#pragma unroll
    for (int r = 0; r < 4; ++r)
        outp[(size_t)(n0 + ty + r * 8) * K + k0 + tx] = f2b(T[tx][ty + r * 8]);
}

// ---------------------------------------------------------------------------
// MFMA GEMM: C = A(MxK bf16, row-major) @ Bt^T (Bt is NxK bf16) [+bias]
// Tile 64x64, BK=32, 256 threads = 4 waves (2x2), wave = 32x32 = 2x2 frags.
// MODE 0: f32 out + bias. MODE 1: bf16 out + bias + relu.
// ---------------------------------------------------------------------------
template <int MODE>
__global__ __launch_bounds__(256)
void mmfma(const unsigned short* __restrict__ A, const unsigned short* __restrict__ Bt,
           const float* __restrict__ bias, void* __restrict__ Cout,
           int M, int N, int K) {
    __shared__ unsigned short As[64 * 40];
    __shared__ unsigned short Bs[64 * 40];
    int tid = threadIdx.x;
    int wid = tid >> 6, l = tid & 63;
    int wr = wid >> 1, wc = wid & 1;
    int lr = l & 15, lg = l >> 4;
    int m0 = blockIdx.y * 64, n0 = blockIdx.x * 64;
    int row = tid >> 2, seg = tid & 3;

    f32x4 acc[2][2];
#pragma unroll
    for (int i = 0; i < 2; ++i)
#pragma unroll
        for (int j = 0; j < 2; ++j) acc[i][j] = (f32x4)(0.f);

    for (int k0 = 0; k0 < K; k0 += 32) {
        int4 av = *reinterpret_cast<const int4*>(A  + (size_t)(m0 + row) * K + k0 + seg * 8);
        int4 bv = *reinterpret_cast<const int4*>(Bt + (size_t)(n0 + row) * K + k0 + seg * 8);
        __syncthreads();
        *reinterpret_cast<int4*>(As + row * 40 + seg * 8) = av;
        *reinterpret_cast<int4*>(Bs + row * 40 + seg * 8) = bv;
        __syncthreads();
        s16x8 af[2], bf[2];
#pragma unroll
        for (int i = 0; i < 2; ++i)
            af[i] = *reinterpret_cast<const s16x8*>(As + (wr * 32 + i * 16 + lr) * 40 + lg * 8);
#pragma unroll
        for (int j = 0; j < 2; ++j)
            bf[j] = *reinterpret_cast<const s16x8*>(Bs + (wc * 32 + j * 16 + lr) * 40 + lg * 8);
#pragma unroll
        for (int i = 0; i < 2; ++i)
#pragma unroll
            for (int j = 0; j < 2; ++j)
                acc[i][j] = __builtin_amdgcn_mfma_f32_16x16x32_bf16(af[i], bf[j], acc[i][j], 0, 0, 0);
    }

#pragma unroll
    for (int i = 0; i < 2; ++i)
#pragma unroll
        for (int j = 0; j < 2; ++j) {
            int col = n0 + wc * 32 + j * 16 + lr;
            float bv = bias ? bias[col] : 0.f;
#pragma unroll
            for (int q = 0; q < 4; ++q) {
                int r = m0 + wr * 32 + i * 16 + lg * 4 + q;
                float v = acc[i][j][q] + bv;
                if (MODE == 1) {
                    v = fmaxf(v, 0.f);
                    ((unsigned short*)Cout)[(size_t)r * N + col] = f2b(v);
                } else {
                    ((float*)Cout)[(size_t)r * N + col] = v;
                }
            }
        }
}

// ---------------------------------------------------------------------------
// Fused QKV MFMA GEMM: same structure, 3 B matrices sharing the A tile.
// Output head-major f32: dst[((n*8+hh)*128 + r)*32 + dk]
// ---------------------------------------------------------------------------
__global__ __launch_bounds__(256)
void qkv_mfma(const unsigned short* __restrict__ A,
              const unsigned short* __restrict__ Bq,
              const unsigned short* __restrict__ Bk,
              const unsigned short* __restrict__ Bv,
              float* __restrict__ Oq, float* __restrict__ Ok, float* __restrict__ Ov) {
    const int K = DD, N = DD;
    __shared__ unsigned short As[64 * 40];
    __shared__ unsigned short Bs[3][64 * 40];
    int tid = threadIdx.x;
    int wid = tid >> 6, l = tid & 63;
    int wr = wid >> 1, wc = wid & 1;
    int lr = l & 15, lg = l >> 4;
    int m0 = blockIdx.y * 64, n0 = blockIdx.x * 64;
    int row = tid >> 2, seg = tid & 3;

    f32x4 acc[3][2][2];
#pragma unroll
    for (int s = 0; s < 3; ++s)
#pragma unroll
        for (int i = 0; i < 2; ++i)
#pragma unroll
            for (int j = 0; j < 2; ++j) acc[s][i][j] = (f32x4)(0.f);

    for (int k0 = 0; k0 < K; k0 += 32) {
        size_t boff = (size_t)(n0 + row) * K + k0 + seg * 8;
        int4 av  = *reinterpret_cast<const int4*>(A  + (size_t)(m0 + row) * K + k0 + seg * 8);
        int4 bq  = *reinterpret_cast<const int4*>(Bq + boff);
        int4 bk  = *reinterpret_cast<const int4*>(Bk + boff);
        int4 bv2 = *reinterpret_cast<const int4*>(Bv + boff);
        __syncthreads();
        *reinterpret_cast<int4*>(As + row * 40 + seg * 8) = av;
        *reinterpret_cast<int4*>(Bs[0] + row * 40 + seg * 8) = bq;
        *reinterpret_cast<int4*>(Bs[1] + row * 40 + seg * 8) = bk;
        *reinterpret_cast<int4*>(Bs[2] + row * 40 + seg * 8) = bv2;
        __syncthreads();
        s16x8 af[2];
#pragma unroll
        for (int i = 0; i < 2; ++i)
            af[i] = *reinterpret_cast<const s16x8*>(As + (wr * 32 + i * 16 + lr) * 40 + lg * 8);
#pragma unroll
        for (int s = 0; s < 3; ++s) {
            s16x8 bf[2];
#pragma unroll
            for (int j = 0; j < 2; ++j)
                bf[j] = *reinterpret_cast<const s16x8*>(Bs[s] + (wc * 32 + j * 16 + lr) * 40 + lg * 8);
#pragma unroll
            for (int i = 0; i < 2; ++i)
#pragma unroll
                for (int j = 0; j < 2; ++j)
                    acc[s][i][j] = __builtin_amdgcn_mfma_f32_16x16x32_bf16(af[i], bf[j], acc[s][i][j], 0, 0, 0);
        }
    }

    float* dsts[3] = {Oq, Ok, Ov};
#pragma unroll
    for (int s = 0; s < 3; ++s) {
        float* dst = dsts[s];
#pragma unroll
        for (int i = 0; i < 2; ++i)
#pragma unroll
            for (int j = 0; j < 2; ++j) {
                int col = n0 + wc * 32 + j * 16 + lr;
                int hh = col >> 5, dk = col & 31;
#pragma unroll
                for (int q = 0; q < 4; ++q) {
                    int r = m0 + wr * 32 + i * 16 + lg * 4 + q;
                    int n = r >> 7, rl = r & 127;
                    dst[(((size_t)(n * HH + hh) * LL + rl) * DK) + dk] = acc[s][i][j][q];
                }
            }
    }
}

// ---------------------------------------------------------------------------
// Fused attention: score (dot+mixer) -> mask -> softmax -> PV ; out bf16 attc
// grid (N*H*4), block 256 (4 waves); block owns 32 rows of one (n,h).
// ---------------------------------------------------------------------------
__global__ __launch_bounds__(256, 4)
void fattn(const float* __restrict__ qh, const float* __restrict__ kh,
           const float* __restrict__ vh, const float* __restrict__ cost,
           const unsigned char* __restrict__ mask,
           const float* __restrict__ m1w, const float* __restrict__ m1b,
           const float* __restrict__ m2w, const float* __restrict__ m2b,
           unsigned short* __restrict__ attc) {
    int blk = blockIdx.x;
    int bh  = blk >> 2;              // n*H + hh
    int rq  = blk & 3;
    int n = bh >> 3, hh = bh & 7;
    int tid = threadIdx.x;
    int lane = tid & 63, wid = tid >> 6;

    __shared__ float Qt[32 * 33];
    __shared__ float Vs[128 * 36];
    __shared__ float Ps[32 * 132];
    __shared__ float w10[MS], w11[MS], b1s[MS], w2s[MS];

    // stage Q (32 rows) and V (128 rows) into LDS
    {
        const float4* qb4 = reinterpret_cast<const float4*>(
            qh + ((size_t)bh * LL + rq * 32) * DK);
        float4 qv = qb4[tid];
        int r = tid >> 3, c = (tid & 7) * 4;
        float* qd = &Qt[r * 33 + c];
        qd[0] = qv.x; qd[1] = qv.y; qd[2] = qv.z; qd[3] = qv.w;
        const float4* vb4 = reinterpret_cast<const float4*>(vh + (size_t)bh * LL * DK);
#pragma unroll
        for (int it = 0; it < 4; ++it) {
            int idx = tid + it * 256;
            float4 vv = vb4[idx];
            int vr = idx >> 3, vc = (idx & 7) * 4;
            *reinterpret_cast<float4*>(&Vs[vr * 36 + vc]) = vv;
        }
    }
    if (tid < MS) {
        w10[tid] = m1w[(hh * 2 + 0) * MS + tid];
        w11[tid] = m1w[(hh * 2 + 1) * MS + tid];
        b1s[tid] = m1b[hh * MS + tid];
        w2s[tid] = m2w[hh * MS + tid];
    }
    // K rows for this lane's two columns -> registers
    const float* kb = kh + (size_t)bh * LL * DK;
    float k0[DK], k1[DK];
    {
        const float4* k4a = reinterpret_cast<const float4*>(kb + (size_t)lane * DK);
        const float4* k4b = reinterpret_cast<const float4*>(kb + (size_t)(lane + 64) * DK);
#pragma unroll
        for (int j = 0; j < 8; ++j) {
            float4 a = k4a[j], b = k4b[j];
            k0[j * 4] = a.x; k0[j * 4 + 1] = a.y; k0[j * 4 + 2] = a.z; k0[j * 4 + 3] = a.w;
            k1[j * 4] = b.x; k1[j * 4 + 1] = b.y; k1[j * 4 + 2] = b.z; k1[j * 4 + 3] = b.w;
        }
    }
    // preload cost + mask for this wave's 8 rows
    float pc0[8], pc1[8];
    int pm0 = 0, pm1 = 0;
#pragma unroll
    for (int i = 0; i < 8; ++i) {
        int r = rq * 32 + wid * 8 + i;
        size_t ro = ((size_t)n * LL + r) * LL;
        pc0[i] = cost[ro + lane];
        pc1[i] = cost[ro + 64 + lane];
        pm0 |= (mask[ro + lane] ? 1 : 0) << i;
        pm1 |= (mask[ro + 64 + lane] ? 1 : 0) << i;
    }
    __syncthreads();

    float b2v = m2b[hh];
    const float scale = 0.17677669529663687f;   // 1/sqrt(32)

#pragma unroll
    for (int i = 0; i < 8; ++i) {
        int rloc = wid * 8 + i;
        float d0 = 0.f, d1 = 0.f;
#pragma unroll
        for (int d = 0; d < DK; ++d) {
            float qd = Qt[rloc * 33 + d];
            d0 += qd * k0[d];
            d1 += qd * k1[d];
        }
        d0 *= scale; d1 *= scale;
        float c0 = pc0[i], c1 = pc1[i];
        float s0 = b2v, s1 = b2v;
#pragma unroll
        for (int m = 0; m < MS; ++m) {
            s0 += fmaxf(d0 * w10[m] + c0 * w11[m] + b1s[m], 0.f) * w2s[m];
            s1 += fmaxf(d1 * w10[m] + c1 * w11[m] + b1s[m], 0.f) * w2s[m];
        }
        if ((pm0 >> i) & 1) s0 = -1e9f;
        if ((pm1 >> i) & 1) s1 = -1e9f;

        float mx = fmaxf(s0, s1);
#pragma unroll
        for (int o = 32; o; o >>= 1) mx = fmaxf(mx, __shfl_xor(mx, o));
        float e0 = __expf(s0 - mx), e1 = __expf(s1 - mx);
        float sum = e0 + e1;
#pragma unroll
        for (int o = 32; o; o >>= 1) sum += __shfl_xor(sum, o);
        float inv = 1.f / sum;
        Ps[rloc * 132 + lane]      = e0 * inv;
        Ps[rloc * 132 + 64 + lane] = e1 * inv;
    }
    __syncthreads();

    // PV: thread -> (r = tid>>3, d0 = (tid&7)*4)
    {
        int r = tid >> 3, d0 = (tid & 7) * 4;
        float ox = 0.f, oy = 0.f, oz = 0.f, ow = 0.f;
#pragma unroll 4
        for (int c = 0; c < LL; ++c) {
            float p = Ps[r * 132 + c];
            float4 v = *reinterpret_cast<const float4*>(&Vs[c * 36 + d0]);
            ox += p * v.x; oy += p * v.y; oz += p * v.z; ow += p * v.w;
        }
        size_t off = ((size_t)(n * LL + rq * 32 + r)) * DD + hh * DK + d0;
        ushort4 u;
        u.x = f2b(ox); u.y = f2b(oy); u.z = f2b(oz); u.w = f2b(ow);
        *reinterpret_cast<ushort4*>(attc + off) = u;
    }
}

// ---------------------------------------------------------------------------
// out = LayerNorm(a + b) * g + be ; writes f32 out and bf16 mirror
// ---------------------------------------------------------------------------
__global__ __launch_bounds__(256)
void add_ln(const float* __restrict__ a, const float* __restrict__ b,
            const float* __restrict__ g, const float* __restrict__ be,
            float* __restrict__ out, unsigned short* __restrict__ outb) {
    int m = blockIdx.x;
    int j = threadIdx.x;
    float x = a[(size_t)m * DD + j] + b[(size_t)m * DD + j];
    __shared__ float red[4];
    int wid = j >> 6;
    float s = x;
#pragma unroll
    for (int o = 32; o; o >>= 1) s += __shfl_xor(s, o);
    if ((j & 63) == 0) red[wid] = s;
    __syncthreads();
    float mean = (red[0] + red[1] + red[2] + red[3]) * (1.0f / 256.0f);
    float d = x - mean;
    float s2 = d * d;
#pragma unroll
    for (int o = 32; o; o >>= 1) s2 += __shfl_xor(s2, o);
    __syncthreads();
    if ((j & 63) == 0) red[wid] = s2;
    __syncthreads();
    float var = (red[0] + red[1] + red[2] + red[3]) * (1.0f / 256.0f);
    float r = d / sqrtf(var + 1e-5f) * g[j] + be[j];
    out[(size_t)m * DD + j] = r;
    outb[(size_t)m * DD + j] = f2b(r);
}

// ---------------------------------------------------------------------------
extern "C" void kernel_launch(void* const* d_in, const int* in_sizes, int n_in,
                              void* d_out, int out_size, void* d_ws, size_t ws_size,
                              hipStream_t stream) {
    const float* vehicles = (const float*)d_in[0];
    const float* fleet    = (const float*)d_in[1];
    const float* Wproj    = (const float*)d_in[2];
    const float* bproj    = (const float*)d_in[3];
    const float* Wq       = (const float*)d_in[4];
    const float* Wk       = (const float*)d_in[5];
    const float* Wv       = (const float*)d_in[6];
    const float* m1w      = (const float*)d_in[7];
    const float* m1b      = (const float*)d_in[8];
    const float* m2w      = (const float*)d_in[9];
    const float* m2b      = (const float*)d_in[10];
    const float* Wo       = (const float*)d_in[11];
    const float* bo       = (const float*)d_in[12];
    const float* n1_g     = (const float*)d_in[13];
    const float* n1_b     = (const float*)d_in[14];
    const float* ff1_w    = (const float*)d_in[15];
    const float* ff1_b    = (const float*)d_in[16];
    const float* ff2_w    = (const float*)d_in[17];
    const float* ff2_b    = (const float*)d_in[18];
    const float* n2_g     = (const float*)d_in[19];
    const float* n2_b     = (const float*)d_in[20];

    const size_t MROWS = (size_t)NB * LL;           // 8192
    const size_t HSZ   = MROWS * DD;                // 2,097,152

    float* ws = (float*)d_ws;
    float* h    = ws;                                // HSZ
    float* tmp  = h + HSZ;                           // HSZ
    float* qh   = tmp + HSZ;                         // HSZ
    float* kh   = qh + HSZ;                          // HSZ
    float* vh   = kh + HSZ;                          // HSZ
    float* cost = vh + HSZ;                          // 1,048,576
    unsigned short* hb    = (unsigned short*)(cost + 1048576);      // HSZ bf16
    unsigned short* attc  = hb + HSZ;                               // HSZ bf16
    unsigned short* ffmid = attc + HSZ;                             // M*FF bf16
    unsigned short* Wt    = ffmid + MROWS * FF;                     // 3*786432 bf16
    unsigned char* mask   = (unsigned char*)(Wt + 3 * 786432);      // M*L bytes

    const long WLS = 786432;   // per-layer transposed-weight stride (elems)

    // preprocessing
    pack_cost<<<1024, 256, 0, stream>>>(fleet, cost);
    proj_kernel<<<MROWS, 256, 0, stream>>>(vehicles, Wproj, bproj, h, hb);
    knn2<<<2048, 256, 0, stream>>>(cost, mask);

    transposeW<<<dim3(8, 8, 3),  256, 0, stream>>>(Wq,    Wt + 0,      DD, DD, DD * DD, WLS);
    transposeW<<<dim3(8, 8, 3),  256, 0, stream>>>(Wk,    Wt + 65536,  DD, DD, DD * DD, WLS);
    transposeW<<<dim3(8, 8, 3),  256, 0, stream>>>(Wv,    Wt + 131072, DD, DD, DD * DD, WLS);
    transposeW<<<dim3(8, 8, 3),  256, 0, stream>>>(Wo,    Wt + 196608, DD, DD, DD * DD, WLS);
    transposeW<<<dim3(32, 8, 3), 256, 0, stream>>>(ff1_w, Wt + 262144, DD, FF, DD * FF, WLS);
    transposeW<<<dim3(8, 32, 3), 256, 0, stream>>>(ff2_w, Wt + 524288, FF, DD, FF * DD, WLS);

    dim3 g256(4, 128);    // N=256, M=8192, 64x64 tiles
    dim3 g1024(16, 128);  // N=1024

    for (int i = 0; i < LC; ++i) {
        const unsigned short* wt = Wt + (size_t)i * WLS;

        qkv_mfma<<<g256, 256, 0, stream>>>(hb, wt, wt + 65536, wt + 131072, qh, kh, vh);

        fattn<<<NB * HH * 4, 256, 0, stream>>>(
            qh, kh, vh, cost, mask,
            m1w + (size_t)i * HH * 2 * MS, m1b + (size_t)i * HH * MS,
            m2w + (size_t)i * HH * MS,     m2b + (size_t)i * HH,
            attc);

        mmfma<0><<<g256, 256, 0, stream>>>(attc, wt + 196608, bo + (size_t)i * DD,
                                           tmp, (int)MROWS, DD, DD);
        add_ln<<<MROWS, 256, 0, stream>>>(h, tmp, n1_g + (size_t)i * DD,
                                          n1_b + (size_t)i * DD, h, hb);

        mmfma<1><<<g1024, 256, 0, stream>>>(hb, wt + 262144, ff1_b + (size_t)i * FF,
                                            ffmid, (int)MROWS, FF, DD);
        mmfma<0><<<g256, 256, 0, stream>>>(ffmid, wt + 524288, ff2_b + (size_t)i * DD,
                                           tmp, (int)MROWS, DD, FF);

        float* dst = (i == LC - 1) ? (float*)d_out : h;
        add_ln<<<MROWS, 256, 0, stream>>>(h, tmp, n2_g + (size_t)i * DD,
                                          n2_b + (size_t)i * DD, dst, hb);
    }
}

// Round 4
// 323.597 us; speedup vs baseline: 4.5441x; 1.6810x over previous
//
#include <hip/hip_runtime.h>
#include <math.h>

// Problem constants
#define NB 64    // N batch
#define LL 128   // L
#define DV 16
#define DD 256   // D
#define HH 8     // heads
#define DK 32    // D/H
#define FF 1024
#define LC 3
#define KNN 6
#define MS 16

typedef __attribute__((ext_vector_type(8))) short s16x8;   // 8 bf16 (4 VGPR)
typedef __attribute__((ext_vector_type(4))) float f32x4;   // MFMA acc

static __device__ inline unsigned short f2b(float x) {
    union { float f; unsigned int u; } v; v.f = x;
    unsigned int r = (v.u + 0x7FFFu + ((v.u >> 16) & 1u)) >> 16;
    return (unsigned short)r;
}

// ---------------------------------------------------------------------------
// Input projection: h = veh @ Wp + bp ; writes f32 h and bf16 mirror hb
// ---------------------------------------------------------------------------
__global__ __launch_bounds__(256)
void proj_kernel(const float* __restrict__ veh, const float* __restrict__ Wp,
                 const float* __restrict__ bp, float* __restrict__ h,
                 unsigned short* __restrict__ hb) {
    int m = blockIdx.x;
    int j = threadIdx.x;
    __shared__ float vrow[DV];
    if (j < DV) vrow[j] = veh[m * DV + j];
    __syncthreads();
    float acc = bp[j];
#pragma unroll
    for (int t = 0; t < DV; ++t) acc += vrow[t] * Wp[t * DD + j];
    h[(size_t)m * DD + j] = acc;
    hb[(size_t)m * DD + j] = f2b(acc);
}

// ---------------------------------------------------------------------------
// Pack cost = edges[...,0] into contiguous (N,L,L)
// ---------------------------------------------------------------------------
__global__ __launch_bounds__(256)
void pack_cost(const float* __restrict__ edges, float* __restrict__ cost) {
    int t = blockIdx.x * 256 + threadIdx.x;
    const float4* e4 = reinterpret_cast<const float4*>(edges) + (size_t)t * 4;
    float4 a = e4[0], b = e4[1], c = e4[2], d = e4[3];
    reinterpret_cast<float4*>(cost)[t] = make_float4(a.x, b.x, c.x, d.x);
}

// ---------------------------------------------------------------------------
// kNN mask (wave-parallel, 6 rounds of shfl min-with-index)
// ---------------------------------------------------------------------------
__global__ __launch_bounds__(256)
void knn2(const float* __restrict__ cost, unsigned char* __restrict__ mask) {
    int row = blockIdx.x * 4 + (threadIdx.x >> 6);
    int lane = threadIdx.x & 63;
    const float* cr = cost + (size_t)row * LL;
    float v0 = cr[lane], v1 = cr[lane + 64];
    int i0 = lane, i1 = lane + 64;
    bool s0 = false, s1 = false;
#pragma unroll
    for (int k = 0; k < KNN; ++k) {
        float v; int i;
        if (v1 < v0) { v = v1; i = i1; } else { v = v0; i = i0; }
#pragma unroll
        for (int o = 1; o < 64; o <<= 1) {
            float ov = __shfl_xor(v, o);
            int oi = __shfl_xor(i, o);
            if (ov < v || (ov == v && oi < i)) { v = ov; i = oi; }
        }
        if (i == i0) { s0 = true; v0 = 3.4e38f; }
        if (i == i1) { s1 = true; v1 = 3.4e38f; }
    }
    mask[(size_t)row * LL + lane]      = s0 ? 0 : 1;
    mask[(size_t)row * LL + lane + 64] = s1 ? 0 : 1;
}

// ---------------------------------------------------------------------------
// Transpose + bf16-cast weights: in (LC, K, N) f32 -> out (LC, N, K) bf16
// ---------------------------------------------------------------------------
__global__ __launch_bounds__(256)
void transposeW(const float* __restrict__ in, unsigned short* __restrict__ out,
                int K, int N, long in_lstride, long out_lstride) {
    int l = blockIdx.z;
    const float* inp = in + (size_t)l * in_lstride;
    unsigned short* outp = out + (size_t)l * out_lstride;
    int tx = threadIdx.x & 31, ty = threadIdx.x >> 5;   // ty 0..7
    int k0 = blockIdx.y * 32, n0 = blockIdx.x * 32;
    __shared__ float T[32][33];
#pragma unroll
    for (int r = 0; r < 4; ++r)
        T[ty + r * 8][tx] = inp[(size_t)(k0 + ty + r * 8) * N + n0 + tx];
    __syncthreads();
#pragma unroll
    for (int r = 0; r < 4; ++r)
        outp[(size_t)(n0 + ty + r * 8) * K + k0 + tx] = f2b(T[tx][ty + r * 8]);
}

// ---------------------------------------------------------------------------
// MFMA GEMM: C = A(MxK bf16, row-major) @ Bt^T (Bt is NxK bf16) [+bias]
// Tile 64x64, BK=32, 256 threads = 4 waves (2x2), wave = 32x32 = 2x2 frags.
// MODE 0: f32 out + bias. MODE 1: bf16 out + bias + relu.
// ---------------------------------------------------------------------------
template <int MODE>
__global__ __launch_bounds__(256)
void mmfma(const unsigned short* __restrict__ A, const unsigned short* __restrict__ Bt,
           const float* __restrict__ bias, void* __restrict__ Cout,
           int M, int N, int K) {
    __shared__ unsigned short As[64 * 40];
    __shared__ unsigned short Bs[64 * 40];
    int tid = threadIdx.x;
    int wid = tid >> 6, l = tid & 63;
    int wr = wid >> 1, wc = wid & 1;
    int lr = l & 15, lg = l >> 4;
    int m0 = blockIdx.y * 64, n0 = blockIdx.x * 64;
    int row = tid >> 2, seg = tid & 3;

    f32x4 acc[2][2];
#pragma unroll
    for (int i = 0; i < 2; ++i)
#pragma unroll
        for (int j = 0; j < 2; ++j) acc[i][j] = (f32x4)(0.f);

    for (int k0 = 0; k0 < K; k0 += 32) {
        int4 av = *reinterpret_cast<const int4*>(A  + (size_t)(m0 + row) * K + k0 + seg * 8);
        int4 bv = *reinterpret_cast<const int4*>(Bt + (size_t)(n0 + row) * K + k0 + seg * 8);
        __syncthreads();
        *reinterpret_cast<int4*>(As + row * 40 + seg * 8) = av;
        *reinterpret_cast<int4*>(Bs + row * 40 + seg * 8) = bv;
        __syncthreads();
        s16x8 af[2], bf[2];
#pragma unroll
        for (int i = 0; i < 2; ++i)
            af[i] = *reinterpret_cast<const s16x8*>(As + (wr * 32 + i * 16 + lr) * 40 + lg * 8);
#pragma unroll
        for (int j = 0; j < 2; ++j)
            bf[j] = *reinterpret_cast<const s16x8*>(Bs + (wc * 32 + j * 16 + lr) * 40 + lg * 8);
#pragma unroll
        for (int i = 0; i < 2; ++i)
#pragma unroll
            for (int j = 0; j < 2; ++j)
                acc[i][j] = __builtin_amdgcn_mfma_f32_16x16x32_bf16(af[i], bf[j], acc[i][j], 0, 0, 0);
    }

#pragma unroll
    for (int i = 0; i < 2; ++i)
#pragma unroll
        for (int j = 0; j < 2; ++j) {
            int col = n0 + wc * 32 + j * 16 + lr;
            float bv = bias ? bias[col] : 0.f;
#pragma unroll
            for (int q = 0; q < 4; ++q) {
                int r = m0 + wr * 32 + i * 16 + lg * 4 + q;
                float v = acc[i][j][q] + bv;
                if (MODE == 1) {
                    v = fmaxf(v, 0.f);
                    ((unsigned short*)Cout)[(size_t)r * N + col] = f2b(v);
                } else {
                    ((float*)Cout)[(size_t)r * N + col] = v;
                }
            }
        }
}

// ---------------------------------------------------------------------------
// Fused QKV MFMA GEMM. Outputs (all bf16):
//   qb,kb head-major [bh][128][32];  vtb transposed [bh][32][128]
// ---------------------------------------------------------------------------
__global__ __launch_bounds__(256)
void qkv_mfma(const unsigned short* __restrict__ A,
              const unsigned short* __restrict__ Bq,
              const unsigned short* __restrict__ Bk,
              const unsigned short* __restrict__ Bv,
              unsigned short* __restrict__ qb, unsigned short* __restrict__ kb,
              unsigned short* __restrict__ vtb) {
    const int K = DD;
    __shared__ unsigned short As[64 * 40];
    __shared__ unsigned short Bs[3][64 * 40];
    int tid = threadIdx.x;
    int wid = tid >> 6, l = tid & 63;
    int wr = wid >> 1, wc = wid & 1;
    int lr = l & 15, lg = l >> 4;
    int m0 = blockIdx.y * 64, n0 = blockIdx.x * 64;
    int row = tid >> 2, seg = tid & 3;

    f32x4 acc[3][2][2];
#pragma unroll
    for (int s = 0; s < 3; ++s)
#pragma unroll
        for (int i = 0; i < 2; ++i)
#pragma unroll
            for (int j = 0; j < 2; ++j) acc[s][i][j] = (f32x4)(0.f);

    for (int k0 = 0; k0 < K; k0 += 32) {
        size_t boff = (size_t)(n0 + row) * K + k0 + seg * 8;
        int4 av  = *reinterpret_cast<const int4*>(A  + (size_t)(m0 + row) * K + k0 + seg * 8);
        int4 bq  = *reinterpret_cast<const int4*>(Bq + boff);
        int4 bk  = *reinterpret_cast<const int4*>(Bk + boff);
        int4 bv2 = *reinterpret_cast<const int4*>(Bv + boff);
        __syncthreads();
        *reinterpret_cast<int4*>(As + row * 40 + seg * 8) = av;
        *reinterpret_cast<int4*>(Bs[0] + row * 40 + seg * 8) = bq;
        *reinterpret_cast<int4*>(Bs[1] + row * 40 + seg * 8) = bk;
        *reinterpret_cast<int4*>(Bs[2] + row * 40 + seg * 8) = bv2;
        __syncthreads();
        s16x8 af[2];
#pragma unroll
        for (int i = 0; i < 2; ++i)
            af[i] = *reinterpret_cast<const s16x8*>(As + (wr * 32 + i * 16 + lr) * 40 + lg * 8);
#pragma unroll
        for (int s = 0; s < 3; ++s) {
            s16x8 bf[2];
#pragma unroll
            for (int j = 0; j < 2; ++j)
                bf[j] = *reinterpret_cast<const s16x8*>(Bs[s] + (wc * 32 + j * 16 + lr) * 40 + lg * 8);
#pragma unroll
            for (int i = 0; i < 2; ++i)
#pragma unroll
                for (int j = 0; j < 2; ++j)
                    acc[s][i][j] = __builtin_amdgcn_mfma_f32_16x16x32_bf16(af[i], bf[j], acc[s][i][j], 0, 0, 0);
        }
    }

#pragma unroll
    for (int i = 0; i < 2; ++i)
#pragma unroll
        for (int j = 0; j < 2; ++j) {
            int col = n0 + wc * 32 + j * 16 + lr;
            int hh = col >> 5, dk = col & 31;
            int rbase = m0 + wr * 32 + i * 16 + lg * 4;
            int nn = rbase >> 7, rl = rbase & 127;
            size_t ho = ((size_t)(nn * HH + hh) * LL + rl) * DK + dk;
#pragma unroll
            for (int q = 0; q < 4; ++q) {
                qb[ho + (size_t)q * DK] = f2b(acc[0][i][j][q]);
                kb[ho + (size_t)q * DK] = f2b(acc[1][i][j][q]);
            }
            ushort4 u;
            u.x = f2b(acc[2][i][j][0]); u.y = f2b(acc[2][i][j][1]);
            u.z = f2b(acc[2][i][j][2]); u.w = f2b(acc[2][i][j][3]);
            *reinterpret_cast<ushort4*>(
                vtb + ((size_t)(nn * HH + hh) * DK + dk) * LL + rl) = u;
        }
}

// ---------------------------------------------------------------------------
// Fused attention v3 (MFMA): QK^T -> mixer -> mask -> softmax -> PV
// grid = N*H*2 (2 blocks per (n,h), 64 q-rows each), block 256 = 4 waves.
// Wave w owns 16 q-rows. Row's 128 cols live in one 16-lane group -> shfl
// softmax, no block barriers after staging.
// ---------------------------------------------------------------------------
__global__ __launch_bounds__(256, 4)
void fattn3(const unsigned short* __restrict__ qb, const unsigned short* __restrict__ kb,
            const unsigned short* __restrict__ vtb, const float* __restrict__ cost,
            const unsigned char* __restrict__ mask,
            const float* __restrict__ m1w, const float* __restrict__ m1b,
            const float* __restrict__ m2w, const float* __restrict__ m2b,
            unsigned short* __restrict__ attc) {
    int bh = blockIdx.x >> 1, half = blockIdx.x & 1;
    int n = bh >> 3, hh = bh & 7;
    int tid = threadIdx.x;
    int w = tid >> 6, l = tid & 63;
    int lr = l & 15, lg = l >> 4;

    __shared__ unsigned short Kbs[128 * 40];   // K rows, stride 40
    __shared__ unsigned short Vts[32 * 136];   // V^T rows (d-major), stride 136
    __shared__ unsigned short Ps[64 * 136];    // P bf16, stride 136

    // stage K (128x32) and Vt (32x128), bf16
    const unsigned short* kg = kb + (size_t)bh * LL * DK;
    const unsigned short* vg = vtb + (size_t)bh * DK * LL;
#pragma unroll
    for (int it = 0; it < 2; ++it) {
        int task = tid + it * 256;
        int kr = task >> 2, ks2 = task & 3;
        *reinterpret_cast<int4*>(&Kbs[kr * 40 + ks2 * 8]) =
            *reinterpret_cast<const int4*>(kg + kr * 32 + ks2 * 8);
        int vr = task >> 4, vs2 = task & 15;
        *reinterpret_cast<int4*>(&Vts[vr * 136 + vs2 * 8]) =
            *reinterpret_cast<const int4*>(vg + vr * 128 + vs2 * 8);
    }
    __syncthreads();

    int r0 = half * 64 + w * 16;               // first q-row of this wave
    // QK^T: 1 A-frag (global), 8 B-frags (LDS), 8 MFMA
    s16x8 aq = *reinterpret_cast<const s16x8*>(
        qb + ((size_t)bh * LL + r0 + lr) * DK + lg * 8);
    f32x4 acc[8];
#pragma unroll
    for (int j = 0; j < 8; ++j) acc[j] = (f32x4)(0.f);
#pragma unroll
    for (int j = 0; j < 8; ++j) {
        s16x8 bk = *reinterpret_cast<const s16x8*>(&Kbs[(j * 16 + lr) * 40 + lg * 8]);
        acc[j] = __builtin_amdgcn_mfma_f32_16x16x32_bf16(aq, bk, acc[j], 0, 0, 0);
    }

    // prefetch cost + mask for this lane's 32 (row,col) elements
    int rbase = r0 + lg * 4;                   // rows rbase..rbase+3
    const float* crow = cost + (size_t)n * LL * LL;
    const unsigned char* mrow = mask + (size_t)n * LL * LL;
    float pc[8][4];
    unsigned mbits = 0;
#pragma unroll
    for (int j = 0; j < 8; ++j)
#pragma unroll
        for (int q = 0; q < 4; ++q) {
            int off = (rbase + q) * LL + j * 16 + lr;
            pc[j][q] = crow[off];
            mbits |= (unsigned)(mrow[off] != 0) << (j * 4 + q);
        }

    // mixer MLP on scores (weights via block-uniform scalar loads)
    const float scale = 0.17677669529663687f;  // 1/sqrt(32)
    const float* w0g = m1w + (hh * 2 + 0) * MS;
    const float* w1g = m1w + (hh * 2 + 1) * MS;
    const float* b1g = m1b + hh * MS;
    const float* w2g = m2w + hh * MS;
    float b2v = m2b[hh];
    float sreg[8][4];
#pragma unroll
    for (int j = 0; j < 8; ++j)
#pragma unroll
        for (int q = 0; q < 4; ++q) sreg[j][q] = b2v;
#pragma unroll
    for (int m = 0; m < MS; ++m) {
        float w0 = w0g[m] * scale;             // fold dot-scale into w0
        float w1 = w1g[m], bb = b1g[m], w2 = w2g[m];
#pragma unroll
        for (int j = 0; j < 8; ++j)
#pragma unroll
            for (int q = 0; q < 4; ++q)
                sreg[j][q] += fmaxf(acc[j][q] * w0 + pc[j][q] * w1 + bb, 0.f) * w2;
    }
#pragma unroll
    for (int j = 0; j < 8; ++j)
#pragma unroll
        for (int q = 0; q < 4; ++q)
            if ((mbits >> (j * 4 + q)) & 1) sreg[j][q] = -1e9f;

    // softmax per row (16-lane group shfl) + P -> bf16 LDS
#pragma unroll
    for (int q = 0; q < 4; ++q) {
        float mx = sreg[0][q];
#pragma unroll
        for (int j = 1; j < 8; ++j) mx = fmaxf(mx, sreg[j][q]);
#pragma unroll
        for (int o = 1; o < 16; o <<= 1) mx = fmaxf(mx, __shfl_xor(mx, o));
        float e[8], sum = 0.f;
#pragma unroll
        for (int j = 0; j < 8; ++j) { e[j] = __expf(sreg[j][q] - mx); sum += e[j]; }
#pragma unroll
        for (int o = 1; o < 16; o <<= 1) sum += __shfl_xor(sum, o);
        float inv = 1.f / sum;
        int prow = (w * 16 + lg * 4 + q) * 136;
#pragma unroll
        for (int j = 0; j < 8; ++j)
            Ps[prow + j * 16 + lr] = f2b(e[j] * inv);
    }
    // Ps rows are wave-private: no block barrier needed (compiler orders LDS).

    // PV: P(16x128) @ V(128x32) per wave -> 8 MFMA
    f32x4 av[2];
    av[0] = (f32x4)(0.f); av[1] = (f32x4)(0.f);
#pragma unroll
    for (int ks = 0; ks < 4; ++ks) {
        s16x8 ap = *reinterpret_cast<const s16x8*>(&Ps[(w * 16 + lr) * 136 + ks * 32 + lg * 8]);
#pragma unroll
        for (int jn = 0; jn < 2; ++jn) {
            s16x8 bv = *reinterpret_cast<const s16x8*>(&Vts[(jn * 16 + lr) * 136 + ks * 32 + lg * 8]);
            av[jn] = __builtin_amdgcn_mfma_f32_16x16x32_bf16(ap, bv, av[jn], 0, 0, 0);
        }
    }

    // epilogue: attc[(n*L + r)*D + hh*32 + d], bf16
#pragma unroll
    for (int jn = 0; jn < 2; ++jn) {
        int d = jn * 16 + lr;
#pragma unroll
        for (int q = 0; q < 4; ++q) {
            int r = r0 + lg * 4 + q;
            attc[((size_t)(n * LL + r)) * DD + hh * DK + d] = f2b(av[jn][q]);
        }
    }
}

// ---------------------------------------------------------------------------
// out = LayerNorm(a + b) * g + be ; writes f32 out and bf16 mirror
// ---------------------------------------------------------------------------
__global__ __launch_bounds__(256)
void add_ln(const float* __restrict__ a, const float* __restrict__ b,
            const float* __restrict__ g, const float* __restrict__ be,
            float* __restrict__ out, unsigned short* __restrict__ outb) {
    int m = blockIdx.x;
    int j = threadIdx.x;
    float x = a[(size_t)m * DD + j] + b[(size_t)m * DD + j];
    __shared__ float red[4];
    int wid = j >> 6;
    float s = x;
#pragma unroll
    for (int o = 32; o; o >>= 1) s += __shfl_xor(s, o);
    if ((j & 63) == 0) red[wid] = s;
    __syncthreads();
    float mean = (red[0] + red[1] + red[2] + red[3]) * (1.0f / 256.0f);
    float d = x - mean;
    float s2 = d * d;
#pragma unroll
    for (int o = 32; o; o >>= 1) s2 += __shfl_xor(s2, o);
    __syncthreads();
    if ((j & 63) == 0) red[wid] = s2;
    __syncthreads();
    float var = (red[0] + red[1] + red[2] + red[3]) * (1.0f / 256.0f);
    float r = d / sqrtf(var + 1e-5f) * g[j] + be[j];
    out[(size_t)m * DD + j] = r;
    outb[(size_t)m * DD + j] = f2b(r);
}

// ---------------------------------------------------------------------------
extern "C" void kernel_launch(void* const* d_in, const int* in_sizes, int n_in,
                              void* d_out, int out_size, void* d_ws, size_t ws_size,
                              hipStream_t stream) {
    const float* vehicles = (const float*)d_in[0];
    const float* fleet    = (const float*)d_in[1];
    const float* Wproj    = (const float*)d_in[2];
    const float* bproj    = (const float*)d_in[3];
    const float* Wq       = (const float*)d_in[4];
    const float* Wk       = (const float*)d_in[5];
    const float* Wv       = (const float*)d_in[6];
    const float* m1w      = (const float*)d_in[7];
    const float* m1b      = (const float*)d_in[8];
    const float* m2w      = (const float*)d_in[9];
    const float* m2b      = (const float*)d_in[10];
    const float* Wo       = (const float*)d_in[11];
    const float* bo       = (const float*)d_in[12];
    const float* n1_g     = (const float*)d_in[13];
    const float* n1_b     = (const float*)d_in[14];
    const float* ff1_w    = (const float*)d_in[15];
    const float* ff1_b    = (const float*)d_in[16];
    const float* ff2_w    = (const float*)d_in[17];
    const float* ff2_b    = (const float*)d_in[18];
    const float* n2_g     = (const float*)d_in[19];
    const float* n2_b     = (const float*)d_in[20];

    const size_t MROWS = (size_t)NB * LL;           // 8192
    const size_t HSZ   = MROWS * DD;                // 2,097,152

    float* ws = (float*)d_ws;
    float* h    = ws;                                // HSZ f32
    float* tmp  = h + HSZ;                           // HSZ f32
    float* cost = tmp + HSZ;                         // 1,048,576 f32
    unsigned short* hb    = (unsigned short*)(cost + 1048576);      // HSZ bf16
    unsigned short* attc  = hb + HSZ;                               // HSZ bf16
    unsigned short* qbb   = attc + HSZ;                             // HSZ bf16
    unsigned short* kbb   = qbb + HSZ;                              // HSZ bf16
    unsigned short* vtb   = kbb + HSZ;                              // HSZ bf16
    unsigned short* ffmid = vtb + HSZ;                              // M*FF bf16
    unsigned short* Wt    = ffmid + MROWS * FF;                     // 3*786432 bf16
    unsigned char* mask   = (unsigned char*)(Wt + 3 * 786432);      // M*L bytes

    const long WLS = 786432;   // per-layer transposed-weight stride (elems)

    // preprocessing
    pack_cost<<<1024, 256, 0, stream>>>(fleet, cost);
    proj_kernel<<<MROWS, 256, 0, stream>>>(vehicles, Wproj, bproj, h, hb);
    knn2<<<2048, 256, 0, stream>>>(cost, mask);

    transposeW<<<dim3(8, 8, 3),  256, 0, stream>>>(Wq,    Wt + 0,      DD, DD, DD * DD, WLS);
    transposeW<<<dim3(8, 8, 3),  256, 0, stream>>>(Wk,    Wt + 65536,  DD, DD, DD * DD, WLS);
    transposeW<<<dim3(8, 8, 3),  256, 0, stream>>>(Wv,    Wt + 131072, DD, DD, DD * DD, WLS);
    transposeW<<<dim3(8, 8, 3),  256, 0, stream>>>(Wo,    Wt + 196608, DD, DD, DD * DD, WLS);
    transposeW<<<dim3(32, 8, 3), 256, 0, stream>>>(ff1_w, Wt + 262144, DD, FF, DD * FF, WLS);
    transposeW<<<dim3(8, 32, 3), 256, 0, stream>>>(ff2_w, Wt + 524288, FF, DD, FF * DD, WLS);

    dim3 g256(4, 128);    // N=256, M=8192, 64x64 tiles
    dim3 g1024(16, 128);  // N=1024

    for (int i = 0; i < LC; ++i) {
        const unsigned short* wt = Wt + (size_t)i * WLS;

        qkv_mfma<<<g256, 256, 0, stream>>>(hb, wt, wt + 65536, wt + 131072,
                                           qbb, kbb, vtb);

        fattn3<<<NB * HH * 2, 256, 0, stream>>>(
            qbb, kbb, vtb, cost, mask,
            m1w + (size_t)i * HH * 2 * MS, m1b + (size_t)i * HH * MS,
            m2w + (size_t)i * HH * MS,     m2b + (size_t)i * HH,
            attc);

        mmfma<0><<<g256, 256, 0, stream>>>(attc, wt + 196608, bo + (size_t)i * DD,
                                           tmp, (int)MROWS, DD, DD);
        add_ln<<<MROWS, 256, 0, stream>>>(h, tmp, n1_g + (size_t)i * DD,
                                          n1_b + (size_t)i * DD, h, hb);

        mmfma<1><<<g1024, 256, 0, stream>>>(hb, wt + 262144, ff1_b + (size_t)i * FF,
                                            ffmid, (int)MROWS, FF, DD);
        mmfma<0><<<g256, 256, 0, stream>>>(ffmid, wt + 524288, ff2_b + (size_t)i * DD,
                                           tmp, (int)MROWS, DD, FF);

        float* dst = (i == LC - 1) ? (float*)d_out : h;
        add_ln<<<MROWS, 256, 0, stream>>>(h, tmp, n2_g + (size_t)i * DD,
                                          n2_b + (size_t)i * DD, dst, hb);
    }
}

// Round 5
// 322.627 us; speedup vs baseline: 4.5577x; 1.0030x over previous
//
#include <hip/hip_runtime.h>
#include <math.h>

// Problem constants
#define NB 64    // N batch
#define LL 128   // L
#define DV 16
#define DD 256   // D
#define HH 8     // heads
#define DK 32    // D/H
#define FF 1024
#define LC 3
#define KNN 6
#define MS 16

typedef __attribute__((ext_vector_type(8))) short s16x8;   // 8 bf16 (4 VGPR)
typedef __attribute__((ext_vector_type(4))) float f32x4;   // MFMA acc

static __device__ inline unsigned short f2b(float x) {
    union { float f; unsigned int u; } v; v.f = x;
    unsigned int r = (v.u + 0x7FFFu + ((v.u >> 16) & 1u)) >> 16;
    return (unsigned short)r;
}

// ---------------------------------------------------------------------------
// Input projection: h = veh @ Wp + bp ; writes f32 h and bf16 mirror hb
// ---------------------------------------------------------------------------
__global__ __launch_bounds__(256)
void proj_kernel(const float* __restrict__ veh, const float* __restrict__ Wp,
                 const float* __restrict__ bp, float* __restrict__ h,
                 unsigned short* __restrict__ hb) {
    int m = blockIdx.x;
    int j = threadIdx.x;
    __shared__ float vrow[DV];
    if (j < DV) vrow[j] = veh[m * DV + j];
    __syncthreads();
    float acc = bp[j];
#pragma unroll
    for (int t = 0; t < DV; ++t) acc += vrow[t] * Wp[t * DD + j];
    h[(size_t)m * DD + j] = acc;
    hb[(size_t)m * DD + j] = f2b(acc);
}

// ---------------------------------------------------------------------------
// Pack cost = edges[...,0] into contiguous (N,L,L)
// ---------------------------------------------------------------------------
__global__ __launch_bounds__(256)
void pack_cost(const float* __restrict__ edges, float* __restrict__ cost) {
    int t = blockIdx.x * 256 + threadIdx.x;
    const float4* e4 = reinterpret_cast<const float4*>(edges) + (size_t)t * 4;
    float4 a = e4[0], b = e4[1], c = e4[2], d = e4[3];
    reinterpret_cast<float4*>(cost)[t] = make_float4(a.x, b.x, c.x, d.x);
}

// ---------------------------------------------------------------------------
// kNN mask as u64 bitmap: mb64[row][0]=cols 0..63, [1]=cols 64..127; bit=1
// means BLOCKED. Wave-parallel min-with-index, ballot to build the bitmap.
// ---------------------------------------------------------------------------
__global__ __launch_bounds__(256)
void knn2(const float* __restrict__ cost, unsigned long long* __restrict__ mb64) {
    int row = blockIdx.x * 4 + (threadIdx.x >> 6);
    int lane = threadIdx.x & 63;
    const float* cr = cost + (size_t)row * LL;
    float v0 = cr[lane], v1 = cr[lane + 64];
    int i0 = lane, i1 = lane + 64;
    bool s0 = false, s1 = false;
#pragma unroll
    for (int k = 0; k < KNN; ++k) {
        float v; int i;
        if (v1 < v0) { v = v1; i = i1; } else { v = v0; i = i0; }
#pragma unroll
        for (int o = 1; o < 64; o <<= 1) {
            float ov = __shfl_xor(v, o);
            int oi = __shfl_xor(i, o);
            if (ov < v || (ov == v && oi < i)) { v = ov; i = oi; }
        }
        if (i == i0) { s0 = true; v0 = 3.4e38f; }
        if (i == i1) { s1 = true; v1 = 3.4e38f; }
    }
    unsigned long long b0 = __ballot(s0);   // selected cols 0..63
    unsigned long long b1 = __ballot(s1);   // selected cols 64..127
    if (lane == 0) {
        mb64[(size_t)row * 2 + 0] = ~b0;
        mb64[(size_t)row * 2 + 1] = ~b1;
    }
}

// ---------------------------------------------------------------------------
// Transpose + bf16-cast weights: in (LC, K, N) f32 -> out (LC, N, K) bf16
// ---------------------------------------------------------------------------
__global__ __launch_bounds__(256)
void transposeW(const float* __restrict__ in, unsigned short* __restrict__ out,
                int K, int N, long in_lstride, long out_lstride) {
    int l = blockIdx.z;
    const float* inp = in + (size_t)l * in_lstride;
    unsigned short* outp = out + (size_t)l * out_lstride;
    int tx = threadIdx.x & 31, ty = threadIdx.x >> 5;   // ty 0..7
    int k0 = blockIdx.y * 32, n0 = blockIdx.x * 32;
    __shared__ float T[32][33];
#pragma unroll
    for (int r = 0; r < 4; ++r)
        T[ty + r * 8][tx] = inp[(size_t)(k0 + ty + r * 8) * N + n0 + tx];
    __syncthreads();
#pragma unroll
    for (int r = 0; r < 4; ++r)
        outp[(size_t)(n0 + ty + r * 8) * K + k0 + tx] = f2b(T[tx][ty + r * 8]);
}

// ---------------------------------------------------------------------------
// MFMA GEMM, 128x64 tile: C = A(MxK bf16) @ Bt^T (Bt NxK bf16) + bias
// 256 threads = 4 waves; wave w = rows w*32..w*32+31, all 64 cols.
// 8 MFMA per wave per K-step (BK=32). MODE 0: f32 out. MODE 1: bf16+relu.
// ---------------------------------------------------------------------------
template <int MODE>
__global__ __launch_bounds__(256)
void mmfma128(const unsigned short* __restrict__ A, const unsigned short* __restrict__ Bt,
              const float* __restrict__ bias, void* __restrict__ Cout,
              int M, int N, int K) {
    __shared__ unsigned short As[128 * 40];
    __shared__ unsigned short Bs[64 * 40];
    int tid = threadIdx.x;
    int w = tid >> 6, l = tid & 63;
    int lr = l & 15, lg = l >> 4;
    int m0 = blockIdx.y * 128, n0 = blockIdx.x * 64;
    int row = tid >> 2, seg = tid & 3;

    f32x4 acc[2][4];
#pragma unroll
    for (int i = 0; i < 2; ++i)
#pragma unroll
        for (int j = 0; j < 4; ++j) acc[i][j] = (f32x4)(0.f);

    for (int k0 = 0; k0 < K; k0 += 32) {
        int4 a0 = *reinterpret_cast<const int4*>(A  + (size_t)(m0 + row) * K + k0 + seg * 8);
        int4 a1 = *reinterpret_cast<const int4*>(A  + (size_t)(m0 + 64 + row) * K + k0 + seg * 8);
        int4 bv = *reinterpret_cast<const int4*>(Bt + (size_t)(n0 + row) * K + k0 + seg * 8);
        __syncthreads();
        *reinterpret_cast<int4*>(As + row * 40 + seg * 8) = a0;
        *reinterpret_cast<int4*>(As + (64 + row) * 40 + seg * 8) = a1;
        *reinterpret_cast<int4*>(Bs + row * 40 + seg * 8) = bv;
        __syncthreads();
        s16x8 af[2], bf[4];
#pragma unroll
        for (int i = 0; i < 2; ++i)
            af[i] = *reinterpret_cast<const s16x8*>(As + (w * 32 + i * 16 + lr) * 40 + lg * 8);
#pragma unroll
        for (int j = 0; j < 4; ++j)
            bf[j] = *reinterpret_cast<const s16x8*>(Bs + (j * 16 + lr) * 40 + lg * 8);
#pragma unroll
        for (int i = 0; i < 2; ++i)
#pragma unroll
            for (int j = 0; j < 4; ++j)
                acc[i][j] = __builtin_amdgcn_mfma_f32_16x16x32_bf16(af[i], bf[j], acc[i][j], 0, 0, 0);
    }

#pragma unroll
    for (int i = 0; i < 2; ++i)
#pragma unroll
        for (int j = 0; j < 4; ++j) {
            int col = n0 + j * 16 + lr;
            float bv = bias[col];
#pragma unroll
            for (int q = 0; q < 4; ++q) {
                int r = m0 + w * 32 + i * 16 + lg * 4 + q;
                float v = acc[i][j][q] + bv;
                if (MODE == 1) {
                    v = fmaxf(v, 0.f);
                    ((unsigned short*)Cout)[(size_t)r * N + col] = f2b(v);
                } else {
                    ((float*)Cout)[(size_t)r * N + col] = v;
                }
            }
        }
}

// ---------------------------------------------------------------------------
// Fused QKV MFMA GEMM. Outputs (all bf16):
//   qb,kb head-major [bh][128][32];  vtb transposed [bh][32][128]
// ---------------------------------------------------------------------------
__global__ __launch_bounds__(256)
void qkv_mfma(const unsigned short* __restrict__ A,
              const unsigned short* __restrict__ Bq,
              const unsigned short* __restrict__ Bk,
              const unsigned short* __restrict__ Bv,
              unsigned short* __restrict__ qb, unsigned short* __restrict__ kb,
              unsigned short* __restrict__ vtb) {
    const int K = DD;
    __shared__ unsigned short As[64 * 40];
    __shared__ unsigned short Bs[3][64 * 40];
    int tid = threadIdx.x;
    int wid = tid >> 6, l = tid & 63;
    int wr = wid >> 1, wc = wid & 1;
    int lr = l & 15, lg = l >> 4;
    int m0 = blockIdx.y * 64, n0 = blockIdx.x * 64;
    int row = tid >> 2, seg = tid & 3;

    f32x4 acc[3][2][2];
#pragma unroll
    for (int s = 0; s < 3; ++s)
#pragma unroll
        for (int i = 0; i < 2; ++i)
#pragma unroll
            for (int j = 0; j < 2; ++j) acc[s][i][j] = (f32x4)(0.f);

    for (int k0 = 0; k0 < K; k0 += 32) {
        size_t boff = (size_t)(n0 + row) * K + k0 + seg * 8;
        int4 av  = *reinterpret_cast<const int4*>(A  + (size_t)(m0 + row) * K + k0 + seg * 8);
        int4 bq  = *reinterpret_cast<const int4*>(Bq + boff);
        int4 bk  = *reinterpret_cast<const int4*>(Bk + boff);
        int4 bv2 = *reinterpret_cast<const int4*>(Bv + boff);
        __syncthreads();
        *reinterpret_cast<int4*>(As + row * 40 + seg * 8) = av;
        *reinterpret_cast<int4*>(Bs[0] + row * 40 + seg * 8) = bq;
        *reinterpret_cast<int4*>(Bs[1] + row * 40 + seg * 8) = bk;
        *reinterpret_cast<int4*>(Bs[2] + row * 40 + seg * 8) = bv2;
        __syncthreads();
        s16x8 af[2];
#pragma unroll
        for (int i = 0; i < 2; ++i)
            af[i] = *reinterpret_cast<const s16x8*>(As + (wr * 32 + i * 16 + lr) * 40 + lg * 8);
#pragma unroll
        for (int s = 0; s < 3; ++s) {
            s16x8 bf[2];
#pragma unroll
            for (int j = 0; j < 2; ++j)
                bf[j] = *reinterpret_cast<const s16x8*>(Bs[s] + (wc * 32 + j * 16 + lr) * 40 + lg * 8);
#pragma unroll
            for (int i = 0; i < 2; ++i)
#pragma unroll
                for (int j = 0; j < 2; ++j)
                    acc[s][i][j] = __builtin_amdgcn_mfma_f32_16x16x32_bf16(af[i], bf[j], acc[s][i][j], 0, 0, 0);
        }
    }

#pragma unroll
    for (int i = 0; i < 2; ++i)
#pragma unroll
        for (int j = 0; j < 2; ++j) {
            int col = n0 + wc * 32 + j * 16 + lr;
            int hh = col >> 5, dk = col & 31;
            int rbase = m0 + wr * 32 + i * 16 + lg * 4;
            int nn = rbase >> 7, rl = rbase & 127;
            size_t ho = ((size_t)(nn * HH + hh) * LL + rl) * DK + dk;
#pragma unroll
            for (int q = 0; q < 4; ++q) {
                qb[ho + (size_t)q * DK] = f2b(acc[0][i][j][q]);
                kb[ho + (size_t)q * DK] = f2b(acc[1][i][j][q]);
            }
            ushort4 u;
            u.x = f2b(acc[2][i][j][0]); u.y = f2b(acc[2][i][j][1]);
            u.z = f2b(acc[2][i][j][2]); u.w = f2b(acc[2][i][j][3]);
            *reinterpret_cast<ushort4*>(
                vtb + ((size_t)(nn * HH + hh) * DK + dk) * LL + rl) = u;
        }
}

// ---------------------------------------------------------------------------
// Fused attention v4 (MFMA): QK^T -> mixer -> mask -> softmax -> PV
// grid = N*H*2, block 256 = 4 waves; wave owns 16 q-rows.
// cost/mask/Q loads issued BEFORE LDS staging writes so their latency hides
// under ds_write + barrier + QK^T MFMA. Mask is a u64 bitmap (broadcast
// loads). P stored unnormalized; 1/sum folded into the PV epilogue.
// ---------------------------------------------------------------------------
__global__ __launch_bounds__(256)
void fattn4(const unsigned short* __restrict__ qb, const unsigned short* __restrict__ kb,
            const unsigned short* __restrict__ vtb, const float* __restrict__ cost,
            const unsigned long long* __restrict__ mb64,
            const float* __restrict__ m1w, const float* __restrict__ m1b,
            const float* __restrict__ m2w, const float* __restrict__ m2b,
            unsigned short* __restrict__ attc) {
    int bh = blockIdx.x >> 1, half = blockIdx.x & 1;
    int n = bh >> 3, hh = bh & 7;
    int tid = threadIdx.x;
    int w = tid >> 6, l = tid & 63;
    int lr = l & 15, lg = l >> 4;

    __shared__ unsigned short Kbs[128 * 40];   // K rows, stride 40
    __shared__ unsigned short Vts[32 * 136];   // V^T rows (d-major), stride 136
    __shared__ unsigned short Ps[64 * 136];    // P bf16 (unnormalized), stride 136

    // ---- (1) issue staging loads (global -> regs) ----
    const unsigned short* kg = kb + (size_t)bh * LL * DK;
    const unsigned short* vg = vtb + (size_t)bh * DK * LL;
    int4 stK[2], stV[2];
#pragma unroll
    for (int it = 0; it < 2; ++it) {
        int task = tid + it * 256;
        stK[it] = *reinterpret_cast<const int4*>(kg + (task >> 2) * 32 + (task & 3) * 8);
        stV[it] = *reinterpret_cast<const int4*>(vg + (task >> 4) * 128 + (task & 15) * 8);
    }
    // ---- (2) issue Q fragment load ----
    int r0 = half * 64 + w * 16;
    s16x8 aq = *reinterpret_cast<const s16x8*>(
        qb + ((size_t)bh * LL + r0 + lr) * DK + lg * 8);
    // ---- (3) issue cost + mask loads (latency hides under staging/QK^T) ----
    int rbase = r0 + lg * 4;
    const float* crow = cost + (size_t)n * LL * LL;
    float pc[8][4];
#pragma unroll
    for (int j = 0; j < 8; ++j)
#pragma unroll
        for (int q = 0; q < 4; ++q)
            pc[j][q] = crow[(rbase + q) * LL + j * 16 + lr];
    ulonglong2 mrow[4];
    {
        const ulonglong2* mbp = reinterpret_cast<const ulonglong2*>(
            mb64 + (size_t)(n * LL + rbase) * 2);
#pragma unroll
        for (int q = 0; q < 4; ++q) mrow[q] = mbp[q];
    }

    // ---- (4) LDS staging writes ----
#pragma unroll
    for (int it = 0; it < 2; ++it) {
        int task = tid + it * 256;
        *reinterpret_cast<int4*>(&Kbs[(task >> 2) * 40 + (task & 3) * 8]) = stK[it];
        *reinterpret_cast<int4*>(&Vts[(task >> 4) * 136 + (task & 15) * 8]) = stV[it];
    }
    __syncthreads();

    // ---- (5) QK^T: 8 MFMA ----
    f32x4 acc[8];
#pragma unroll
    for (int j = 0; j < 8; ++j) acc[j] = (f32x4)(0.f);
#pragma unroll
    for (int j = 0; j < 8; ++j) {
        s16x8 bk = *reinterpret_cast<const s16x8*>(&Kbs[(j * 16 + lr) * 40 + lg * 8]);
        acc[j] = __builtin_amdgcn_mfma_f32_16x16x32_bf16(aq, bk, acc[j], 0, 0, 0);
    }

    // ---- (6) mixer MLP + mask + softmax ----
    const float scale = 0.17677669529663687f;  // 1/sqrt(32)
    const float* w0g = m1w + (hh * 2 + 0) * MS;
    const float* w1g = m1w + (hh * 2 + 1) * MS;
    const float* b1g = m1b + hh * MS;
    const float* w2g = m2w + hh * MS;
    float b2v = m2b[hh];
    float sreg[8][4];
#pragma unroll
    for (int j = 0; j < 8; ++j)
#pragma unroll
        for (int q = 0; q < 4; ++q) sreg[j][q] = b2v;
#pragma unroll
    for (int m = 0; m < MS; ++m) {
        float w0 = w0g[m] * scale;             // fold dot-scale into w0
        float w1 = w1g[m], bb = b1g[m], w2 = w2g[m];
#pragma unroll
        for (int j = 0; j < 8; ++j)
#pragma unroll
            for (int q = 0; q < 4; ++q)
                sreg[j][q] += fmaxf(acc[j][q] * w0 + pc[j][q] * w1 + bb, 0.f) * w2;
    }
#pragma unroll
    for (int q = 0; q < 4; ++q) {
        unsigned long long lo = mrow[q].x >> lr, hi = mrow[q].y >> lr;
#pragma unroll
        for (int j = 0; j < 8; ++j) {
            unsigned long long mh = (j < 4) ? lo : hi;
            if ((mh >> ((j & 3) * 16)) & 1ull) sreg[j][q] = -1e9f;
        }
    }

    float invq[4];
#pragma unroll
    for (int q = 0; q < 4; ++q) {
        float mx = sreg[0][q];
#pragma unroll
        for (int j = 1; j < 8; ++j) mx = fmaxf(mx, sreg[j][q]);
#pragma unroll
        for (int o = 1; o < 16; o <<= 1) mx = fmaxf(mx, __shfl_xor(mx, o));
        float e[8], sum = 0.f;
#pragma unroll
        for (int j = 0; j < 8; ++j) { e[j] = __expf(sreg[j][q] - mx); sum += e[j]; }
#pragma unroll
        for (int o = 1; o < 16; o <<= 1) sum += __shfl_xor(sum, o);
        invq[q] = 1.f / sum;
        int prow = (w * 16 + lg * 4 + q) * 136;
#pragma unroll
        for (int j = 0; j < 8; ++j)
            Ps[prow + j * 16 + lr] = f2b(e[j]);   // unnormalized
    }
    // Ps rows are wave-private: no block barrier needed.

    // ---- (7) PV: 8 MFMA + inv-scale epilogue ----
    f32x4 av[2];
    av[0] = (f32x4)(0.f); av[1] = (f32x4)(0.f);
#pragma unroll
    for (int ks = 0; ks < 4; ++ks) {
        s16x8 ap = *reinterpret_cast<const s16x8*>(&Ps[(w * 16 + lr) * 136 + ks * 32 + lg * 8]);
#pragma unroll
        for (int jn = 0; jn < 2; ++jn) {
            s16x8 bv = *reinterpret_cast<const s16x8*>(&Vts[(jn * 16 + lr) * 136 + ks * 32 + lg * 8]);
            av[jn] = __builtin_amdgcn_mfma_f32_16x16x32_bf16(ap, bv, av[jn], 0, 0, 0);
        }
    }
#pragma unroll
    for (int jn = 0; jn < 2; ++jn) {
        int d = jn * 16 + lr;
#pragma unroll
        for (int q = 0; q < 4; ++q) {
            int r = r0 + lg * 4 + q;
            attc[((size_t)(n * LL + r)) * DD + hh * DK + d] = f2b(av[jn][q] * invq[q]);
        }
    }
}

// ---------------------------------------------------------------------------
// out = LayerNorm(a + b) * g + be ; writes f32 out and bf16 mirror
// ---------------------------------------------------------------------------
__global__ __launch_bounds__(256)
void add_ln(const float* __restrict__ a, const float* __restrict__ b,
            const float* __restrict__ g, const float* __restrict__ be,
            float* __restrict__ out, unsigned short* __restrict__ outb) {
    int m = blockIdx.x;
    int j = threadIdx.x;
    float x = a[(size_t)m * DD + j] + b[(size_t)m * DD + j];
    __shared__ float red[4];
    int wid = j >> 6;
    float s = x;
#pragma unroll
    for (int o = 32; o; o >>= 1) s += __shfl_xor(s, o);
    if ((j & 63) == 0) red[wid] = s;
    __syncthreads();
    float mean = (red[0] + red[1] + red[2] + red[3]) * (1.0f / 256.0f);
    float d = x - mean;
    float s2 = d * d;
#pragma unroll
    for (int o = 32; o; o >>= 1) s2 += __shfl_xor(s2, o);
    __syncthreads();
    if ((j & 63) == 0) red[wid] = s2;
    __syncthreads();
    float var = (red[0] + red[1] + red[2] + red[3]) * (1.0f / 256.0f);
    float r = d / sqrtf(var + 1e-5f) * g[j] + be[j];
    out[(size_t)m * DD + j] = r;
    outb[(size_t)m * DD + j] = f2b(r);
}

// ---------------------------------------------------------------------------
extern "C" void kernel_launch(void* const* d_in, const int* in_sizes, int n_in,
                              void* d_out, int out_size, void* d_ws, size_t ws_size,
                              hipStream_t stream) {
    const float* vehicles = (const float*)d_in[0];
    const float* fleet    = (const float*)d_in[1];
    const float* Wproj    = (const float*)d_in[2];
    const float* bproj    = (const float*)d_in[3];
    const float* Wq       = (const float*)d_in[4];
    const float* Wk       = (const float*)d_in[5];
    const float* Wv       = (const float*)d_in[6];
    const float* m1w      = (const float*)d_in[7];
    const float* m1b      = (const float*)d_in[8];
    const float* m2w      = (const float*)d_in[9];
    const float* m2b      = (const float*)d_in[10];
    const float* Wo       = (const float*)d_in[11];
    const float* bo       = (const float*)d_in[12];
    const float* n1_g     = (const float*)d_in[13];
    const float* n1_b     = (const float*)d_in[14];
    const float* ff1_w    = (const float*)d_in[15];
    const float* ff1_b    = (const float*)d_in[16];
    const float* ff2_w    = (const float*)d_in[17];
    const float* ff2_b    = (const float*)d_in[18];
    const float* n2_g     = (const float*)d_in[19];
    const float* n2_b     = (const float*)d_in[20];

    const size_t MROWS = (size_t)NB * LL;           // 8192
    const size_t HSZ   = MROWS * DD;                // 2,097,152

    float* ws = (float*)d_ws;
    float* h    = ws;                                // HSZ f32
    float* tmp  = h + HSZ;                           // HSZ f32
    float* cost = tmp + HSZ;                         // 1,048,576 f32
    unsigned short* hb    = (unsigned short*)(cost + 1048576);      // HSZ bf16
    unsigned short* attc  = hb + HSZ;                               // HSZ bf16
    unsigned short* qbb   = attc + HSZ;                             // HSZ bf16
    unsigned short* kbb   = qbb + HSZ;                              // HSZ bf16
    unsigned short* vtb   = kbb + HSZ;                              // HSZ bf16
    unsigned short* ffmid = vtb + HSZ;                              // M*FF bf16
    unsigned short* Wt    = ffmid + MROWS * FF;                     // 3*786432 bf16
    unsigned long long* mb64 = (unsigned long long*)(Wt + 3 * 786432); // 8192*2 u64

    const long WLS = 786432;   // per-layer transposed-weight stride (elems)

    // preprocessing
    pack_cost<<<1024, 256, 0, stream>>>(fleet, cost);
    proj_kernel<<<MROWS, 256, 0, stream>>>(vehicles, Wproj, bproj, h, hb);
    knn2<<<2048, 256, 0, stream>>>(cost, mb64);

    transposeW<<<dim3(8, 8, 3),  256, 0, stream>>>(Wq,    Wt + 0,      DD, DD, DD * DD, WLS);
    transposeW<<<dim3(8, 8, 3),  256, 0, stream>>>(Wk,    Wt + 65536,  DD, DD, DD * DD, WLS);
    transposeW<<<dim3(8, 8, 3),  256, 0, stream>>>(Wv,    Wt + 131072, DD, DD, DD * DD, WLS);
    transposeW<<<dim3(8, 8, 3),  256, 0, stream>>>(Wo,    Wt + 196608, DD, DD, DD * DD, WLS);
    transposeW<<<dim3(32, 8, 3), 256, 0, stream>>>(ff1_w, Wt + 262144, DD, FF, DD * FF, WLS);
    transposeW<<<dim3(8, 32, 3), 256, 0, stream>>>(ff2_w, Wt + 524288, FF, DD, FF * DD, WLS);

    dim3 gq(4, 128);     // qkv: 64x64 tiles
    dim3 g256(4, 64);    // mmfma128: N=256, M=8192 -> 128x64 tiles
    dim3 g1024(16, 64);  // mmfma128: N=1024

    for (int i = 0; i < LC; ++i) {
        const unsigned short* wt = Wt + (size_t)i * WLS;

        qkv_mfma<<<gq, 256, 0, stream>>>(hb, wt, wt + 65536, wt + 131072,
                                         qbb, kbb, vtb);

        fattn4<<<NB * HH * 2, 256, 0, stream>>>(
            qbb, kbb, vtb, cost, mb64,
            m1w + (size_t)i * HH * 2 * MS, m1b + (size_t)i * HH * MS,
            m2w + (size_t)i * HH * MS,     m2b + (size_t)i * HH,
            attc);

        mmfma128<0><<<g256, 256, 0, stream>>>(attc, wt + 196608, bo + (size_t)i * DD,
                                              tmp, (int)MROWS, DD, DD);
        add_ln<<<MROWS, 256, 0, stream>>>(h, tmp, n1_g + (size_t)i * DD,
                                          n1_b + (size_t)i * DD, h, hb);

        mmfma128<1><<<g1024, 256, 0, stream>>>(hb, wt + 262144, ff1_b + (size_t)i * FF,
                                               ffmid, (int)MROWS, FF, DD);
        mmfma128<0><<<g256, 256, 0, stream>>>(ffmid, wt + 524288, ff2_b + (size_t)i * DD,
                                              tmp, (int)MROWS, DD, FF);

        float* dst = (i == LC - 1) ? (float*)d_out : h;
        add_ln<<<MROWS, 256, 0, stream>>>(h, tmp, n2_g + (size_t)i * DD,
                                          n2_b + (size_t)i * DD, dst, hb);
    }
}